// Round 3
// baseline (711.550 us; speedup 1.0000x reference)
//
#include <hip/hip_runtime.h>

#define B_   8
#define N_   4096
#define S_   1024
#define M_   2048
#define D1_  128
#define D2_  256
#define CIN_ 388
#define CPAD 400
#define J_   (B_ * N_)   // 32768
#define BN_EPS 1e-5f

// Unfused fp32 ops — must match reference's expansion-formula rounding exactly;
// prevents hipcc FMA contraction on the distance path.
__device__ __forceinline__ float mulrn(float a, float b) { return __fmul_rn(a, b); }
__device__ __forceinline__ float addrn(float a, float b) { return __fadd_rn(a, b); }
__device__ __forceinline__ float subrn(float a, float b) { return __fsub_rn(a, b); }
__device__ __forceinline__ float norm3(float x, float y, float z) {
    return addrn(addrn(mulrn(x, x), mulrn(y, y)), mulrn(z, z));
}

// ---------------------------------------------------------------------------
// points2 [B][D2][S] -> p2t [B][S][D2]
__global__ __launch_bounds__(256) void k_transpose_p2(const float* __restrict__ p2,
                                                      float* __restrict__ p2t) {
    __shared__ float tile[32][33];
    int b = blockIdx.z;
    int s0 = blockIdx.x * 32, c0 = blockIdx.y * 32;
    int tx = threadIdx.x, ty = threadIdx.y;  // 32 x 8
#pragma unroll
    for (int i = 0; i < 4; i++)
        tile[ty + i * 8][tx] = p2[(size_t)b * D2_ * S_ + (size_t)(c0 + ty + i * 8) * S_ + s0 + tx];
    __syncthreads();
#pragma unroll
    for (int i = 0; i < 4; i++)
        p2t[(size_t)b * S_ * D2_ + (size_t)(s0 + ty + i * 8) * D2_ + c0 + tx] = tile[tx][ty + i * 8];
}

// ---------------------------------------------------------------------------
// W [O][C] -> Wt [Cpad][O], zero-padded rows
__global__ __launch_bounds__(256) void k_prep_w(const float* __restrict__ W,
                                                float* __restrict__ Wt, int O, int C, int Cpad) {
    int i = blockIdx.x * 256 + threadIdx.x;
    if (i >= Cpad * O) return;
    int c = i / O, o = i % O;
    Wt[i] = (c < C) ? W[(size_t)o * C + c] : 0.f;
}

// ---------------------------------------------------------------------------
// Per-point: 3-NN interp + nearest keypoint + assemble X0 [CPAD][J]
// Distances use the reference's expansion formula (sn + sm) - 2*dot with
// unfused left-to-right fp32 — tie decisions then match the reference.
__global__ __launch_bounds__(256) void k_build(const float* __restrict__ xyz1,
                                               const float* __restrict__ xyz2,
                                               const float* __restrict__ points1,
                                               const float* __restrict__ feature,
                                               const float* __restrict__ p2t,
                                               float* __restrict__ X0) {
    __shared__ float s2x[S_], s2y[S_], s2z[S_], s2n[S_];
    __shared__ float fkx[M_], fky[M_], fkz[M_], fkn[M_];
    int b = blockIdx.y;
    int tid = threadIdx.x;
    int n = blockIdx.x * 256 + tid;

    for (int s = tid; s < S_; s += 256) {
        float x = xyz2[(size_t)b * 3 * S_ + 0 * S_ + s];
        float y = xyz2[(size_t)b * 3 * S_ + 1 * S_ + s];
        float z = xyz2[(size_t)b * 3 * S_ + 2 * S_ + s];
        s2x[s] = x; s2y[s] = y; s2z[s] = z;
        s2n[s] = norm3(x, y, z);
    }
    for (int m = tid; m < M_; m += 256) {
        float4 f = *(const float4*)(feature + (size_t)b * M_ * 4 + (size_t)m * 4);
        fkx[m] = f.y; fky[m] = f.z; fkz[m] = f.w;
        fkn[m] = norm3(f.y, f.z, f.w);
    }
    __syncthreads();

    float qx = xyz1[(size_t)b * 3 * N_ + 0 * N_ + n];
    float qy = xyz1[(size_t)b * 3 * N_ + 1 * N_ + n];
    float qz = xyz1[(size_t)b * 3 * N_ + 2 * N_ + n];
    float qn = norm3(qx, qy, qz);

    // top-3 smallest expansion-distances over S (stable: strict <)
    float d0 = 1e30f, d1 = 1e30f, d2 = 1e30f;
    int i0 = 0, i1 = 0, i2 = 0;
    for (int s = 0; s < S_; s++) {
        float dot = addrn(addrn(mulrn(qx, s2x[s]), mulrn(qy, s2y[s])), mulrn(qz, s2z[s]));
        float d = subrn(addrn(qn, s2n[s]), mulrn(2.0f, dot));
        bool l0 = d < d0, l1 = d < d1, l2 = d < d2;
        d2 = l1 ? d1 : (l2 ? d : d2);  i2 = l1 ? i1 : (l2 ? s : i2);
        d1 = l0 ? d0 : (l1 ? d : d1);  i1 = l0 ? i0 : (l1 ? s : i1);
        d0 = l0 ? d  : d0;             i0 = l0 ? s  : i0;
    }
    float w0 = 1.0f / addrn(d0, 1e-8f);
    float w1 = 1.0f / addrn(d1, 1e-8f);
    float w2 = 1.0f / addrn(d2, 1e-8f);
    float wsum = addrn(addrn(w0, w1), w2);
    w0 = w0 / wsum; w1 = w1 / wsum; w2 = w2 / wsum;

    // argmin over M keypoints (expansion distances, first-min on ties)
    float dm = 1e30f; int im = 0;
    for (int m = 0; m < M_; m++) {
        float dot = addrn(addrn(mulrn(qx, fkx[m]), mulrn(qy, fky[m])), mulrn(qz, fkz[m]));
        float d = subrn(addrn(qn, fkn[m]), mulrn(2.0f, dot));
        if (d < dm) { dm = d; im = m; }
    }

    size_t j = (size_t)b * N_ + n;

    // rows 0..127 : points1
    const float* p1 = points1 + (size_t)b * D1_ * N_ + n;
#pragma unroll 8
    for (int c = 0; c < D1_; c++) X0[(size_t)c * J_ + j] = p1[(size_t)c * N_];

    // rows 128..383 : 3-NN interpolated points2 (unfused, left-to-right like ref)
    const float* r0 = p2t + (size_t)b * S_ * D2_ + (size_t)i0 * D2_;
    const float* r1 = p2t + (size_t)b * S_ * D2_ + (size_t)i1 * D2_;
    const float* r2 = p2t + (size_t)b * S_ * D2_ + (size_t)i2 * D2_;
    for (int c = 0; c < D2_; c += 4) {
        float4 a = *(const float4*)(r0 + c);
        float4 bb = *(const float4*)(r1 + c);
        float4 cc = *(const float4*)(r2 + c);
        X0[(size_t)(D1_ + c + 0) * J_ + j] = addrn(addrn(mulrn(a.x, w0), mulrn(bb.x, w1)), mulrn(cc.x, w2));
        X0[(size_t)(D1_ + c + 1) * J_ + j] = addrn(addrn(mulrn(a.y, w0), mulrn(bb.y, w1)), mulrn(cc.y, w2));
        X0[(size_t)(D1_ + c + 2) * J_ + j] = addrn(addrn(mulrn(a.z, w0), mulrn(bb.z, w1)), mulrn(cc.z, w2));
        X0[(size_t)(D1_ + c + 3) * J_ + j] = addrn(addrn(mulrn(a.w, w0), mulrn(bb.w, w1)), mulrn(cc.w, w2));
    }

    // rows 384..387 : nearest keypoint feature (all 4 cols)
    float4 nf = *(const float4*)(feature + (size_t)b * M_ * 4 + (size_t)im * 4);
    X0[(size_t)(384) * J_ + j] = nf.x;
    X0[(size_t)(385) * J_ + j] = nf.y;
    X0[(size_t)(386) * J_ + j] = nf.z;
    X0[(size_t)(387) * J_ + j] = nf.w;

    // pad rows
    for (int c = CIN_; c < CPAD; c++) X0[(size_t)c * J_ + j] = 0.f;
}

// ---------------------------------------------------------------------------
// Y[O][J] = Wt^T X (+bias). Optional per-channel BN+ReLU applied to X on load.
// Wt: [Cpad][O], X: [Cpad][J]. 128x128 tile, 8x8 per thread, BK=16.
__global__ __launch_bounds__(256) void k_gemm(const float* __restrict__ Wt,
                                              const float* __restrict__ X,
                                              const float* __restrict__ bias,
                                              const float* __restrict__ bnA,
                                              const float* __restrict__ bnS,
                                              float* __restrict__ Y,
                                              int O, int Cpad) {
    __shared__ float sW[16][128];
    __shared__ float sX[16][128];
    int tid = threadIdx.x;
    int tx = tid & 15, ty = tid >> 4;
    int j0 = blockIdx.x * 128;
    int o0 = blockIdx.y * 128;
    int lr = tid >> 5;          // 0..7
    int lc = (tid & 31) * 4;    // 0..124

    float acc[8][8];
#pragma unroll
    for (int i = 0; i < 8; i++)
#pragma unroll
        for (int q = 0; q < 8; q++) acc[i][q] = 0.f;

    for (int c0 = 0; c0 < Cpad; c0 += 16) {
#pragma unroll
        for (int h = 0; h < 2; h++) {
            int r = lr + h * 8;
            float4 w4 = *(const float4*)(Wt + (size_t)(c0 + r) * O + o0 + lc);
            float4 x4 = *(const float4*)(X + (size_t)(c0 + r) * J_ + j0 + lc);
            if (bnA) {
                float a = bnA[c0 + r], s = bnS[c0 + r];
                x4.x = fmaxf(a * x4.x + s, 0.f);
                x4.y = fmaxf(a * x4.y + s, 0.f);
                x4.z = fmaxf(a * x4.z + s, 0.f);
                x4.w = fmaxf(a * x4.w + s, 0.f);
            }
            *(float4*)&sW[r][lc] = w4;
            *(float4*)&sX[r][lc] = x4;
        }
        __syncthreads();
#pragma unroll
        for (int k = 0; k < 16; k++) {
            float a[8], bb[8];
            *(float4*)(a)      = *(const float4*)&sW[k][ty * 8];
            *(float4*)(a + 4)  = *(const float4*)&sW[k][ty * 8 + 4];
            *(float4*)(bb)     = *(const float4*)&sX[k][tx * 8];
            *(float4*)(bb + 4) = *(const float4*)&sX[k][tx * 8 + 4];
#pragma unroll
            for (int i = 0; i < 8; i++)
#pragma unroll
                for (int q = 0; q < 8; q++) acc[i][q] += a[i] * bb[q];
        }
        __syncthreads();
    }

#pragma unroll
    for (int i = 0; i < 8; i++) {
        int o = o0 + ty * 8 + i;
        float bi = bias[o];
        float4 v0 = {acc[i][0] + bi, acc[i][1] + bi, acc[i][2] + bi, acc[i][3] + bi};
        float4 v1 = {acc[i][4] + bi, acc[i][5] + bi, acc[i][6] + bi, acc[i][7] + bi};
        *(float4*)(Y + (size_t)o * J_ + j0 + tx * 8) = v0;
        *(float4*)(Y + (size_t)o * J_ + j0 + tx * 8 + 4) = v1;
    }
}

// ---------------------------------------------------------------------------
// Per-channel batch stats -> affine (a, s) with y = a*x + s
__global__ __launch_bounds__(256) void k_stats(const float* __restrict__ T,
                                               const float* __restrict__ g,
                                               const float* __restrict__ be,
                                               float* __restrict__ A,
                                               float* __restrict__ Sh) {
    int o = blockIdx.x;
    int tid = threadIdx.x;
    const float* row = T + (size_t)o * J_;
    float s = 0.f, q = 0.f;
#pragma unroll 4
    for (int i = 0; i < J_ / (256 * 4); i++) {
        float4 v = *(const float4*)(row + ((size_t)i * 256 + tid) * 4);
        s += v.x + v.y + v.z + v.w;
        q += v.x * v.x + v.y * v.y + v.z * v.z + v.w * v.w;
    }
    __shared__ float ss[256], sq[256];
    ss[tid] = s; sq[tid] = q;
    __syncthreads();
    for (int st = 128; st > 0; st >>= 1) {
        if (tid < st) { ss[tid] += ss[tid + st]; sq[tid] += sq[tid + st]; }
        __syncthreads();
    }
    if (tid == 0) {
        float mean = ss[0] / (float)J_;
        float var = sq[0] / (float)J_ - mean * mean;
        float a = g[o] * rsqrtf(var + BN_EPS);
        A[o] = a;
        Sh[o] = be[o] - a * mean;
    }
}

// ---------------------------------------------------------------------------
// Final BN+ReLU and layout to [B][256][N]
__global__ __launch_bounds__(256) void k_final(const float* __restrict__ T2,
                                               const float* __restrict__ A,
                                               const float* __restrict__ Sh,
                                               float* __restrict__ out) {
    int o = blockIdx.y, b = blockIdx.z;
    int n = blockIdx.x * 1024 + threadIdx.x * 4;
    float4 v = *(const float4*)(T2 + (size_t)o * J_ + (size_t)b * N_ + n);
    float a = A[o], s = Sh[o];
    float4 r = {fmaxf(a * v.x + s, 0.f), fmaxf(a * v.y + s, 0.f),
                fmaxf(a * v.z + s, 0.f), fmaxf(a * v.w + s, 0.f)};
    *(float4*)(out + (size_t)b * 256 * N_ + (size_t)o * N_ + n) = r;
}

// ---------------------------------------------------------------------------
extern "C" void kernel_launch(void* const* d_in, const int* in_sizes, int n_in,
                              void* d_out, int out_size, void* d_ws, size_t ws_size,
                              hipStream_t stream) {
    (void)in_sizes; (void)n_in; (void)out_size; (void)ws_size;
    const float* xyz1    = (const float*)d_in[0];
    const float* xyz2    = (const float*)d_in[1];
    const float* points1 = (const float*)d_in[2];
    const float* points2 = (const float*)d_in[3];
    const float* feature = (const float*)d_in[4];
    const float* W0 = (const float*)d_in[5];
    const float* b0 = (const float*)d_in[6];
    const float* g0 = (const float*)d_in[7];
    const float* be0 = (const float*)d_in[8];
    const float* W1 = (const float*)d_in[9];
    const float* b1 = (const float*)d_in[10];
    const float* g1 = (const float*)d_in[11];
    const float* be1 = (const float*)d_in[12];
    const float* W2 = (const float*)d_in[13];
    const float* b2 = (const float*)d_in[14];
    const float* g2 = (const float*)d_in[15];
    const float* be2 = (const float*)d_in[16];

    float* ws = (float*)d_ws;
    size_t off = 0;
    float* p2t = ws + off; off += (size_t)B_ * S_ * D2_;
    float* X0  = ws + off; off += (size_t)CPAD * J_;
    float* T0  = ws + off; off += (size_t)512 * J_;
    float* T1  = ws + off; off += (size_t)512 * J_;
    float* Wt0 = ws + off; off += (size_t)CPAD * 512;
    float* Wt1 = ws + off; off += (size_t)512 * 512;
    float* Wt2 = ws + off; off += (size_t)512 * 256;
    float* A0 = ws + off; off += 512;
    float* S0 = ws + off; off += 512;
    float* A1 = ws + off; off += 512;
    float* S1 = ws + off; off += 512;
    float* A2 = ws + off; off += 512;
    float* S2 = ws + off; off += 512;
    float* T2 = X0;  // reuse (X0 dead after GEMM1)

    k_prep_w<<<dim3((CPAD * 512 + 255) / 256), 256, 0, stream>>>(W0, Wt0, 512, CIN_, CPAD);
    k_prep_w<<<dim3((512 * 512 + 255) / 256), 256, 0, stream>>>(W1, Wt1, 512, 512, 512);
    k_prep_w<<<dim3((512 * 256 + 255) / 256), 256, 0, stream>>>(W2, Wt2, 256, 512, 512);
    k_transpose_p2<<<dim3(S_ / 32, D2_ / 32, B_), dim3(32, 8), 0, stream>>>(points2, p2t);
    k_build<<<dim3(N_ / 256, B_), 256, 0, stream>>>(xyz1, xyz2, points1, feature, p2t, X0);

    k_gemm<<<dim3(J_ / 128, 512 / 128), 256, 0, stream>>>(Wt0, X0, b0, nullptr, nullptr, T0, 512, CPAD);
    k_stats<<<512, 256, 0, stream>>>(T0, g0, be0, A0, S0);
    k_gemm<<<dim3(J_ / 128, 512 / 128), 256, 0, stream>>>(Wt1, T0, b1, A0, S0, T1, 512, 512);
    k_stats<<<512, 256, 0, stream>>>(T1, g1, be1, A1, S1);
    k_gemm<<<dim3(J_ / 128, 256 / 128), 256, 0, stream>>>(Wt2, T1, b2, A1, S1, T2, 256, 512);
    k_stats<<<256, 256, 0, stream>>>(T2, g2, be2, A2, S2);
    k_final<<<dim3(N_ / 1024, 256, B_), 256, 0, stream>>>(T2, A2, S2, (float*)d_out);
}

// Round 4
// 389.648 us; speedup vs baseline: 1.8261x; 1.8261x over previous
//
#include <hip/hip_runtime.h>

#define B_   8
#define N_   4096
#define S_   1024
#define M_   2048
#define D1_  128
#define D2_  256
#define CIN_ 388
#define KP0  416          // K of layer0, padded to 13*32
#define K12  512          // K of layers 1,2
#define J_   (B_ * N_)    // 32768
#define BN_EPS 1e-5f

typedef __bf16 bf16x8 __attribute__((ext_vector_type(8)));
typedef float  f32x4  __attribute__((ext_vector_type(4)));
typedef unsigned short ushort_t;

__device__ __forceinline__ float mulrn(float a, float b) { return __fmul_rn(a, b); }
__device__ __forceinline__ float addrn(float a, float b) { return __fadd_rn(a, b); }
__device__ __forceinline__ float subrn(float a, float b) { return __fsub_rn(a, b); }
__device__ __forceinline__ float norm3(float x, float y, float z) {
    return addrn(addrn(mulrn(x, x), mulrn(y, y)), mulrn(z, z));
}
__device__ __forceinline__ ushort_t f2bf(float f) {  // RNE
    unsigned int u = __float_as_uint(f);
    return (ushort_t)((u + 0x7FFFu + ((u >> 16) & 1u)) >> 16);
}
__device__ __forceinline__ float bf2f(ushort_t u) {
    return __uint_as_float(((unsigned int)u) << 16);
}

// ---------------------------------------------------------------------------
// points2 [B][D2][S] -> p2t [B][S][D2]  (fp32, feeds exact interp math)
__global__ __launch_bounds__(256) void k_transpose_p2(const float* __restrict__ p2,
                                                      float* __restrict__ p2t) {
    __shared__ float tile[32][33];
    int b = blockIdx.z;
    int s0 = blockIdx.x * 32, c0 = blockIdx.y * 32;
    int tx = threadIdx.x, ty = threadIdx.y;  // 32 x 8
#pragma unroll
    for (int i = 0; i < 4; i++)
        tile[ty + i * 8][tx] = p2[(size_t)b * D2_ * S_ + (size_t)(c0 + ty + i * 8) * S_ + s0 + tx];
    __syncthreads();
#pragma unroll
    for (int i = 0; i < 4; i++)
        p2t[(size_t)b * S_ * D2_ + (size_t)(s0 + ty + i * 8) * D2_ + c0 + tx] = tile[tx][ty + i * 8];
}

// ---------------------------------------------------------------------------
// W [O][C] fp32 -> Wb [O][Kp] bf16, zero-padded cols (already k-contiguous)
__global__ __launch_bounds__(256) void k_prep_w(const float* __restrict__ W,
                                                ushort_t* __restrict__ Wb, int O, int C, int Kp) {
    int i = blockIdx.x * 256 + threadIdx.x;
    if (i >= O * Kp) return;
    int o = i / Kp, k = i - o * Kp;
    Wb[i] = (k < C) ? f2bf(W[(size_t)o * C + k]) : (ushort_t)0;
}

// ---------------------------------------------------------------------------
// zero the stats accumulators (2560 floats)
__global__ void k_zero(float* p, int n) {
    int i = blockIdx.x * 256 + threadIdx.x;
    if (i < n) p[i] = 0.f;
}

// ---------------------------------------------------------------------------
// Per-point: 3-NN interp + nearest keypoint -> XT [J][KP0] bf16 rows.
// Distance math identical to the passing fp32 version (expansion formula,
// unfused, left-to-right) so selections match the reference.
__global__ __launch_bounds__(256) void k_build(const float* __restrict__ xyz1,
                                               const float* __restrict__ xyz2,
                                               const float* __restrict__ points1,
                                               const float* __restrict__ feature,
                                               const float* __restrict__ p2t,
                                               ushort_t* __restrict__ XT) {
    __shared__ float s2x[S_], s2y[S_], s2z[S_], s2n[S_];
    __shared__ float fkx[M_], fky[M_], fkz[M_], fkn[M_];
    int b = blockIdx.y;
    int tid = threadIdx.x;
    int n = blockIdx.x * 256 + tid;

    for (int s = tid; s < S_; s += 256) {
        float x = xyz2[(size_t)b * 3 * S_ + 0 * S_ + s];
        float y = xyz2[(size_t)b * 3 * S_ + 1 * S_ + s];
        float z = xyz2[(size_t)b * 3 * S_ + 2 * S_ + s];
        s2x[s] = x; s2y[s] = y; s2z[s] = z;
        s2n[s] = norm3(x, y, z);
    }
    for (int m = tid; m < M_; m += 256) {
        float4 f = *(const float4*)(feature + (size_t)b * M_ * 4 + (size_t)m * 4);
        fkx[m] = f.y; fky[m] = f.z; fkz[m] = f.w;
        fkn[m] = norm3(f.y, f.z, f.w);
    }
    __syncthreads();

    float qx = xyz1[(size_t)b * 3 * N_ + 0 * N_ + n];
    float qy = xyz1[(size_t)b * 3 * N_ + 1 * N_ + n];
    float qz = xyz1[(size_t)b * 3 * N_ + 2 * N_ + n];
    float qn = norm3(qx, qy, qz);

    float d0 = 1e30f, d1 = 1e30f, d2 = 1e30f;
    int i0 = 0, i1 = 0, i2 = 0;
    for (int s = 0; s < S_; s++) {
        float dot = addrn(addrn(mulrn(qx, s2x[s]), mulrn(qy, s2y[s])), mulrn(qz, s2z[s]));
        float d = subrn(addrn(qn, s2n[s]), mulrn(2.0f, dot));
        bool l0 = d < d0, l1 = d < d1, l2 = d < d2;
        d2 = l1 ? d1 : (l2 ? d : d2);  i2 = l1 ? i1 : (l2 ? s : i2);
        d1 = l0 ? d0 : (l1 ? d : d1);  i1 = l0 ? i0 : (l1 ? s : i1);
        d0 = l0 ? d  : d0;             i0 = l0 ? s  : i0;
    }
    float w0 = 1.0f / addrn(d0, 1e-8f);
    float w1 = 1.0f / addrn(d1, 1e-8f);
    float w2 = 1.0f / addrn(d2, 1e-8f);
    float wsum = addrn(addrn(w0, w1), w2);
    w0 = w0 / wsum; w1 = w1 / wsum; w2 = w2 / wsum;

    float dm = 1e30f; int im = 0;
    for (int m = 0; m < M_; m++) {
        float dot = addrn(addrn(mulrn(qx, fkx[m]), mulrn(qy, fky[m])), mulrn(qz, fkz[m]));
        float d = subrn(addrn(qn, fkn[m]), mulrn(2.0f, dot));
        if (d < dm) { dm = d; im = m; }
    }

    size_t j = (size_t)b * N_ + n;
    ushort_t* xr = XT + j * KP0;

    // rows 0..127 : points1 (coalesced loads across threads), bf16x8 stores
    const float* p1 = points1 + (size_t)b * D1_ * N_ + n;
    for (int c = 0; c < D1_; c += 8) {
        ushort_t tmp[8];
#pragma unroll
        for (int t = 0; t < 8; t++) tmp[t] = f2bf(p1[(size_t)(c + t) * N_]);
        *(uint4*)&xr[c] = *(uint4*)tmp;
    }

    // 128..383 : 3-NN interpolated points2 (unfused fp32, then quantize)
    const float* r0 = p2t + (size_t)b * S_ * D2_ + (size_t)i0 * D2_;
    const float* r1 = p2t + (size_t)b * S_ * D2_ + (size_t)i1 * D2_;
    const float* r2 = p2t + (size_t)b * S_ * D2_ + (size_t)i2 * D2_;
    for (int c = 0; c < D2_; c += 8) {
        ushort_t tmp[8];
#pragma unroll
        for (int h = 0; h < 2; h++) {
            float4 a = *(const float4*)(r0 + c + h * 4);
            float4 bb = *(const float4*)(r1 + c + h * 4);
            float4 cc = *(const float4*)(r2 + c + h * 4);
            tmp[h * 4 + 0] = f2bf(addrn(addrn(mulrn(a.x, w0), mulrn(bb.x, w1)), mulrn(cc.x, w2)));
            tmp[h * 4 + 1] = f2bf(addrn(addrn(mulrn(a.y, w0), mulrn(bb.y, w1)), mulrn(cc.y, w2)));
            tmp[h * 4 + 2] = f2bf(addrn(addrn(mulrn(a.z, w0), mulrn(bb.z, w1)), mulrn(cc.z, w2)));
            tmp[h * 4 + 3] = f2bf(addrn(addrn(mulrn(a.w, w0), mulrn(bb.w, w1)), mulrn(cc.w, w2)));
        }
        *(uint4*)&xr[D1_ + c] = *(uint4*)tmp;
    }

    // 384..415 : keypoint feature + zero pad
    float4 nf = *(const float4*)(feature + (size_t)b * M_ * 4 + (size_t)im * 4);
    {
        ushort_t tmp[8] = {f2bf(nf.x), f2bf(nf.y), f2bf(nf.z), f2bf(nf.w), 0, 0, 0, 0};
        *(uint4*)&xr[384] = *(uint4*)tmp;
        uint4 z = {0, 0, 0, 0};
        *(uint4*)&xr[392] = z;
        *(uint4*)&xr[400] = z;
        *(uint4*)&xr[408] = z;
    }
}

// ---------------------------------------------------------------------------
// bf16 MFMA GEMM: T[j][o] = X[j][:]·W[o][:] + bias[o], fused per-channel
// sum/sumsq atomics for BN stats.
// X: [J][Kt] bf16, W: [Nout][Kt] bf16. Tile 128(j)x128(o), 4 waves, BK=32.
// LDS tiles [128 rows][32 k] with slot swizzle g^((row>>1)&3) (2-way = free).
__global__ __launch_bounds__(256) void k_gemm(const ushort_t* __restrict__ Xb,
                                              const ushort_t* __restrict__ Wb,
                                              const float* __restrict__ bias,
                                              ushort_t* __restrict__ T,
                                              float* __restrict__ gsum,
                                              float* __restrict__ gsq,
                                              int Kt, int Nout) {
    __shared__ ushort_t sA[2][128 * 32];
    __shared__ ushort_t sB[2][128 * 32];
    __shared__ float redS[128][2], redQ[128][2];

    int tid = threadIdx.x;
    int l = tid & 63;
    int w = tid >> 6;
    int wr = w >> 1, wc = w & 1;
    int j0 = blockIdx.x * 128, o0 = blockIdx.y * 128;

    f32x4 acc[4][4] = {};
    int nt = Kt >> 5;

    auto stage = [&](int buf, int k0) {
#pragma unroll
        for (int e = 0; e < 2; ++e) {
            int i = e * 256 + tid;
            int row = i >> 2;
            int g = (i & 3) ^ ((row >> 1) & 3);   // pre-swizzled source chunk
            const ushort_t* ga = Xb + (size_t)(j0 + row) * Kt + k0 + g * 8;
            __builtin_amdgcn_global_load_lds(
                (const __attribute__((address_space(1))) void*)ga,
                (__attribute__((address_space(3))) void*)&sA[buf][i * 8], 16, 0, 0);
            const ushort_t* gb = Wb + (size_t)(o0 + row) * Kt + k0 + g * 8;
            __builtin_amdgcn_global_load_lds(
                (const __attribute__((address_space(1))) void*)gb,
                (__attribute__((address_space(3))) void*)&sB[buf][i * 8], 16, 0, 0);
        }
    };

    stage(0, 0);
    __syncthreads();

    for (int t = 0; t < nt; ++t) {
        int cur = t & 1;
        if (t + 1 < nt) stage(cur ^ 1, (t + 1) << 5);

        bf16x8 av[4], bv[4];
#pragma unroll
        for (int mi = 0; mi < 4; ++mi) {
            int r = wr * 64 + mi * 16 + (l & 15);
            int sl = (l >> 4) ^ ((r >> 1) & 3);
            av[mi] = *(const bf16x8*)&sA[cur][r * 32 + sl * 8];
        }
#pragma unroll
        for (int ni = 0; ni < 4; ++ni) {
            int r = wc * 64 + ni * 16 + (l & 15);
            int sl = (l >> 4) ^ ((r >> 1) & 3);
            bv[ni] = *(const bf16x8*)&sB[cur][r * 32 + sl * 8];
        }
#pragma unroll
        for (int mi = 0; mi < 4; ++mi)
#pragma unroll
            for (int ni = 0; ni < 4; ++ni)
                acc[mi][ni] = __builtin_amdgcn_mfma_f32_16x16x32_bf16(av[mi], bv[ni],
                                                                      acc[mi][ni], 0, 0, 0);
        __syncthreads();
    }

    // Epilogue: bias, quantize-store T[j][o], column partial sums.
    float csum[4], csq[4];
#pragma unroll
    for (int ni = 0; ni < 4; ++ni) { csum[ni] = 0.f; csq[ni] = 0.f; }

#pragma unroll
    for (int ni = 0; ni < 4; ++ni) {
        int o = o0 + wc * 64 + ni * 16 + (l & 15);
        float bi = bias[o];
#pragma unroll
        for (int mi = 0; mi < 4; ++mi) {
            int jb = j0 + wr * 64 + mi * 16 + (l >> 4) * 4;
#pragma unroll
            for (int r = 0; r < 4; ++r) {
                float v = acc[mi][ni][r] + bi;
                csum[ni] += v;
                csq[ni] += v * v;
                T[(size_t)(jb + r) * Nout + o] = f2bf(v);
            }
        }
    }

#pragma unroll
    for (int ni = 0; ni < 4; ++ni) {
        float s = csum[ni], q = csq[ni];
        s += __shfl_xor(s, 16); s += __shfl_xor(s, 32);
        q += __shfl_xor(q, 16); q += __shfl_xor(q, 32);
        if ((l & 48) == 0) {  // lanes 0..15
            redS[wc * 64 + ni * 16 + (l & 15)][wr] = s;
            redQ[wc * 64 + ni * 16 + (l & 15)][wr] = q;
        }
    }
    __syncthreads();
    if (tid < 128) {
        atomicAdd(&gsum[o0 + tid], redS[tid][0] + redS[tid][1]);
        atomicAdd(&gsq[o0 + tid], redQ[tid][0] + redQ[tid][1]);
    }
}

// ---------------------------------------------------------------------------
// sums -> BN affine (a, s): y = a*x + s
__global__ void k_affine(const float* __restrict__ gsum, const float* __restrict__ gsq,
                         const float* __restrict__ g, const float* __restrict__ be,
                         float* __restrict__ A, float* __restrict__ S, int C) {
    int o = blockIdx.x * 256 + threadIdx.x;
    if (o >= C) return;
    float mean = gsum[o] / (float)J_;
    float var = gsq[o] / (float)J_ - mean * mean;
    float a = g[o] * rsqrtf(var + BN_EPS);
    A[o] = a;
    S[o] = be[o] - a * mean;
}

// ---------------------------------------------------------------------------
// In-place BN+ReLU on T [J][512] bf16 (channel = col = idx & 511)
__global__ __launch_bounds__(256) void k_norm(ushort_t* __restrict__ T,
                                              const float* __restrict__ A,
                                              const float* __restrict__ S) {
    size_t idx = ((size_t)blockIdx.x * 256 + threadIdx.x) * 8;
    int o = (int)(idx & 511);
    uint4 v = *(uint4*)&T[idx];
    ushort_t* pu = (ushort_t*)&v;
#pragma unroll
    for (int i = 0; i < 8; i++) {
        float f = bf2f(pu[i]);
        f = fmaxf(A[o + i] * f + S[o + i], 0.f);
        pu[i] = f2bf(f);
    }
    *(uint4*)&T[idx] = v;
}

// ---------------------------------------------------------------------------
// T2 [J][256] bf16 + BN affine + ReLU -> out [B][256][N] fp32 (transpose)
__global__ __launch_bounds__(256) void k_final(const ushort_t* __restrict__ T2,
                                               const float* __restrict__ A,
                                               const float* __restrict__ S,
                                               float* __restrict__ out) {
    __shared__ float tile[64][65];
    int tid = threadIdx.x;
    int jb = blockIdx.z * N_ + blockIdx.x * 64;  // global j of tile row 0
    int o0 = blockIdx.y * 64;

    int r = tid >> 2, cq = (tid & 3) * 16;
    uint4 v = *(const uint4*)&T2[(size_t)(jb + r) * 256 + o0 + cq];
    ushort_t* pu = (ushort_t*)&v;
#pragma unroll
    for (int i = 0; i < 8; i++) {
        int o = o0 + cq + i;
        tile[r][cq + i] = fmaxf(A[o] * bf2f(pu[i]) + S[o], 0.f);
    }
    uint4 v2 = *(const uint4*)&T2[(size_t)(jb + r) * 256 + o0 + cq + 8];
    pu = (ushort_t*)&v2;
#pragma unroll
    for (int i = 0; i < 8; i++) {
        int o = o0 + cq + 8 + i;
        tile[r][cq + 8 + i] = fmaxf(A[o] * bf2f(pu[i]) + S[o], 0.f);
    }
    __syncthreads();

    int ro = tid >> 2, jq = (tid & 3) * 16;
    float* orow = out + ((size_t)blockIdx.z * 256 + o0 + ro) * N_ + blockIdx.x * 64 + jq;
#pragma unroll
    for (int h = 0; h < 4; h++) {
        float4 ov = {tile[jq + h * 4 + 0][ro], tile[jq + h * 4 + 1][ro],
                     tile[jq + h * 4 + 2][ro], tile[jq + h * 4 + 3][ro]};
        *(float4*)(orow + h * 4) = ov;
    }
}

// ---------------------------------------------------------------------------
extern "C" void kernel_launch(void* const* d_in, const int* in_sizes, int n_in,
                              void* d_out, int out_size, void* d_ws, size_t ws_size,
                              hipStream_t stream) {
    (void)in_sizes; (void)n_in; (void)out_size; (void)ws_size;
    const float* xyz1    = (const float*)d_in[0];
    const float* xyz2    = (const float*)d_in[1];
    const float* points1 = (const float*)d_in[2];
    const float* points2 = (const float*)d_in[3];
    const float* feature = (const float*)d_in[4];
    const float* W0 = (const float*)d_in[5];
    const float* b0 = (const float*)d_in[6];
    const float* g0 = (const float*)d_in[7];
    const float* be0 = (const float*)d_in[8];
    const float* W1 = (const float*)d_in[9];
    const float* b1 = (const float*)d_in[10];
    const float* g1 = (const float*)d_in[11];
    const float* be1 = (const float*)d_in[12];
    const float* W2 = (const float*)d_in[13];
    const float* b2 = (const float*)d_in[14];
    const float* g2 = (const float*)d_in[15];
    const float* be2 = (const float*)d_in[16];

    char* ws = (char*)d_ws;
    size_t off = 0;
    auto carve = [&](size_t bytes) { char* p = ws + off; off += (bytes + 255) & ~(size_t)255; return p; };

    ushort_t* XT  = (ushort_t*)carve((size_t)J_ * KP0 * 2);
    ushort_t* T0  = (ushort_t*)carve((size_t)J_ * 512 * 2);
    ushort_t* T1  = (ushort_t*)carve((size_t)J_ * 512 * 2);
    ushort_t* T2  = (ushort_t*)carve((size_t)J_ * 256 * 2);
    float*    p2t = (float*)carve((size_t)B_ * S_ * D2_ * 4);
    ushort_t* Wb0 = (ushort_t*)carve((size_t)512 * KP0 * 2);
    ushort_t* Wb1 = (ushort_t*)carve((size_t)512 * K12 * 2);
    ushort_t* Wb2 = (ushort_t*)carve((size_t)256 * K12 * 2);
    float*    st  = (float*)carve(2560 * 4);   // gs0,gq0,gs1,gq1,gs2,gq2
    float*    af  = (float*)carve(2560 * 4);   // A0,S0,A1,S1,A2,S2
    float *gs0 = st, *gq0 = st + 512, *gs1 = st + 1024, *gq1 = st + 1536, *gs2 = st + 2048, *gq2 = st + 2304;
    float *A0 = af, *S0 = af + 512, *A1 = af + 1024, *S1 = af + 1536, *A2 = af + 2048, *S2 = af + 2304;

    k_zero<<<dim3(10), 256, 0, stream>>>(st, 2560);
    k_prep_w<<<dim3((512 * KP0 + 255) / 256), 256, 0, stream>>>(W0, Wb0, 512, CIN_, KP0);
    k_prep_w<<<dim3((512 * K12 + 255) / 256), 256, 0, stream>>>(W1, Wb1, 512, 512, K12);
    k_prep_w<<<dim3((256 * K12 + 255) / 256), 256, 0, stream>>>(W2, Wb2, 256, 512, K12);
    k_transpose_p2<<<dim3(S_ / 32, D2_ / 32, B_), dim3(32, 8), 0, stream>>>(points2, p2t);
    k_build<<<dim3(N_ / 256, B_), 256, 0, stream>>>(xyz1, xyz2, points1, feature, p2t, XT);

    k_gemm<<<dim3(J_ / 128, 4), 256, 0, stream>>>(XT, Wb0, b0, T0, gs0, gq0, KP0, 512);
    k_affine<<<dim3(2), 256, 0, stream>>>(gs0, gq0, g0, be0, A0, S0, 512);
    k_norm<<<dim3((int)((size_t)J_ * 512 / 8 / 256)), 256, 0, stream>>>(T0, A0, S0);

    k_gemm<<<dim3(J_ / 128, 4), 256, 0, stream>>>(T0, Wb1, b1, T1, gs1, gq1, K12, 512);
    k_affine<<<dim3(2), 256, 0, stream>>>(gs1, gq1, g1, be1, A1, S1, 512);
    k_norm<<<dim3((int)((size_t)J_ * 512 / 8 / 256)), 256, 0, stream>>>(T1, A1, S1);

    k_gemm<<<dim3(J_ / 128, 2), 256, 0, stream>>>(T1, Wb2, b2, T2, gs2, gq2, K12, 256);
    k_affine<<<dim3(1), 256, 0, stream>>>(gs2, gq2, g2, be2, A2, S2, 256);

    k_final<<<dim3(N_ / 64, 4, B_), 256, 0, stream>>>(T2, A2, S2, (float*)d_out);
}

// Round 5
// 240.104 us; speedup vs baseline: 2.9635x; 1.6228x over previous
//
#include <hip/hip_runtime.h>

#define B_   8
#define N_   4096
#define S_   1024
#define M_   2048
#define D1_  128
#define D2_  256
#define CIN_ 388
#define KP0  416          // K of layer0, padded to 13*32
#define K12  512          // K of layers 1,2
#define J_   (B_ * N_)    // 32768
#define BN_EPS 1e-5f

typedef __bf16 bf16x8 __attribute__((ext_vector_type(8)));
typedef float  f32x4  __attribute__((ext_vector_type(4)));
typedef unsigned short ushort_t;

__device__ __forceinline__ float mulrn(float a, float b) { return __fmul_rn(a, b); }
__device__ __forceinline__ float addrn(float a, float b) { return __fadd_rn(a, b); }
__device__ __forceinline__ float subrn(float a, float b) { return __fsub_rn(a, b); }
__device__ __forceinline__ float norm3(float x, float y, float z) {
    return addrn(addrn(mulrn(x, x), mulrn(y, y)), mulrn(z, z));
}
__device__ __forceinline__ ushort_t f2bf(float f) {  // RNE
    unsigned int u = __float_as_uint(f);
    return (ushort_t)((u + 0x7FFFu + ((u >> 16) & 1u)) >> 16);
}
__device__ __forceinline__ float bf2f(ushort_t u) {
    return __uint_as_float(((unsigned int)u) << 16);
}
// lexicographic (d, idx) compare — reproduces stable top-k tie-breaking
__device__ __forceinline__ bool plt(float da, int ia, float db, int ib) {
    return (da < db) || (da == db && ia < ib);
}

// ---------------------------------------------------------------------------
// points2 [B][D2][S] -> p2t [B][S][D2]  (fp32, feeds exact interp math)
__global__ __launch_bounds__(256) void k_transpose_p2(const float* __restrict__ p2,
                                                      float* __restrict__ p2t) {
    __shared__ float tile[32][33];
    int b = blockIdx.z;
    int s0 = blockIdx.x * 32, c0 = blockIdx.y * 32;
    int tx = threadIdx.x, ty = threadIdx.y;  // 32 x 8
#pragma unroll
    for (int i = 0; i < 4; i++)
        tile[ty + i * 8][tx] = p2[(size_t)b * D2_ * S_ + (size_t)(c0 + ty + i * 8) * S_ + s0 + tx];
    __syncthreads();
#pragma unroll
    for (int i = 0; i < 4; i++)
        p2t[(size_t)b * S_ * D2_ + (size_t)(s0 + ty + i * 8) * D2_ + c0 + tx] = tile[tx][ty + i * 8];
}

// ---------------------------------------------------------------------------
// W [O][C] fp32 -> Wb [O][Kp] bf16, zero-padded cols (already k-contiguous)
__global__ __launch_bounds__(256) void k_prep_w(const float* __restrict__ W,
                                                ushort_t* __restrict__ Wb, int O, int C, int Kp) {
    int i = blockIdx.x * 256 + threadIdx.x;
    if (i >= O * Kp) return;
    int o = i / Kp, k = i - o * Kp;
    Wb[i] = (k < C) ? f2bf(W[(size_t)o * C + k]) : (ushort_t)0;
}

// ---------------------------------------------------------------------------
__global__ void k_zero(float* p, int n) {
    int i = blockIdx.x * 256 + threadIdx.x;
    if (i < n) p[i] = 0.f;
}

// ---------------------------------------------------------------------------
// points1 [B][D1][N] fp32 -> XT[j][0:128] bf16 (LDS tile transpose)
// Block: 32 n-values x 128 channels.
__global__ __launch_bounds__(256) void k_p1t(const float* __restrict__ p1,
                                             ushort_t* __restrict__ XT) {
    __shared__ ushort_t tile[32][132];   // 264B rows: 2-4 way banks only
    int b = blockIdx.y;
    int n0 = blockIdx.x * 32;
    int t = threadIdx.x;

    {
        int nl = t & 31, cq = t >> 5;          // cq 0..7
#pragma unroll
        for (int k = 0; k < 16; k++) {
            int c = cq * 16 + k;
            tile[nl][c] = f2bf(p1[(size_t)b * D1_ * N_ + (size_t)c * N_ + n0 + nl]);
        }
    }
    __syncthreads();
    {
        int nl = t >> 3, sub = t & 7;
        size_t j = (size_t)b * N_ + n0 + nl;
#pragma unroll
        for (int k = 0; k < 4; k++) {
            int chunk = k * 8 + sub;           // 8B chunk of the 256B row
            *(uint2*)&XT[j * KP0 + chunk * 4] = *(const uint2*)&tile[nl][chunk * 4];
        }
    }
}

// ---------------------------------------------------------------------------
// One WAVE per query point: lane-parallel top-3 (S) + argmin (M) with
// lexicographic butterfly merges, then wave-parallel interp assembly.
// Distance arithmetic identical (unfused expansion formula) to the passing
// serial version, so selections match the reference.
__global__ __launch_bounds__(256) void k_nn(const float* __restrict__ xyz1,
                                            const float* __restrict__ xyz2,
                                            const float* __restrict__ feature,
                                            const float* __restrict__ p2t,
                                            ushort_t* __restrict__ XT) {
    int b = blockIdx.y;
    int wid = threadIdx.x >> 6;
    int l = threadIdx.x & 63;
    int n = blockIdx.x * 4 + wid;

    const float* s2 = xyz2 + (size_t)b * 3 * S_;
    const float* fb = feature + (size_t)b * M_ * 4;

    float qx = xyz1[(size_t)b * 3 * N_ + n];
    float qy = xyz1[(size_t)b * 3 * N_ + N_ + n];
    float qz = xyz1[(size_t)b * 3 * N_ + 2 * N_ + n];
    float qn = norm3(qx, qy, qz);

    // ---- per-lane top-3 over s = l, l+64, ... (strict < keeps lowest s)
    float d0 = 1e30f, d1 = 1e30f, d2 = 1e30f;
    int i0 = 0, i1 = 0, i2 = 0;
#pragma unroll 4
    for (int t = 0; t < S_ / 64; t++) {
        int s = t * 64 + l;
        float cx = s2[s], cy = s2[S_ + s], cz = s2[2 * S_ + s];
        float cn = norm3(cx, cy, cz);
        float dot = addrn(addrn(mulrn(qx, cx), mulrn(qy, cy)), mulrn(qz, cz));
        float d = subrn(addrn(qn, cn), mulrn(2.0f, dot));
        bool l0 = d < d0, l1 = d < d1, l2 = d < d2;
        d2 = l1 ? d1 : (l2 ? d : d2);  i2 = l1 ? i1 : (l2 ? s : i2);
        d1 = l0 ? d0 : (l1 ? d : d1);  i1 = l0 ? i0 : (l1 ? s : i1);
        d0 = l0 ? d  : d0;             i0 = l0 ? s  : i0;
    }

    // ---- butterfly merge of sorted triples across 64 lanes
#pragma unroll
    for (int off = 1; off < 64; off <<= 1) {
        float e0 = __shfl_xor(d0, off), e1 = __shfl_xor(d1, off), e2 = __shfl_xor(d2, off);
        int   f0 = __shfl_xor(i0, off), f1 = __shfl_xor(i1, off), f2 = __shfl_xor(i2, off);
        // heads
        bool c0 = plt(e0, f0, d0, i0);
        float m0d = c0 ? e0 : d0; int m0i = c0 ? f0 : i0;   // r0 = min(a0,b0)
        float x0d = c0 ? d0 : e0; int x0i = c0 ? i0 : f0;   // max(a0,b0)
        bool c1 = plt(e1, f1, d1, i1);
        float n1d = c1 ? e1 : d1; int n1i = c1 ? f1 : i1;   // min(a1,b1)
        float z1d = c1 ? d1 : e1; int z1i = c1 ? i1 : f1;   // max(a1,b1)
        bool c2 = plt(e2, f2, d2, i2);
        float w2d = c2 ? e2 : d2; int w2i = c2 ? f2 : i2;   // min(a2,b2)
        // r1 = min(x0, n1); t2 = max(x0, n1)
        bool c3 = plt(n1d, n1i, x0d, x0i);
        float r1d = c3 ? n1d : x0d; int r1i = c3 ? n1i : x0i;
        float t2d = c3 ? x0d : n1d; int t2i = c3 ? x0i : n1i;
        // r2 = min(z1, t2, w2)
        bool c4 = plt(t2d, t2i, z1d, z1i);
        float u2d = c4 ? t2d : z1d; int u2i = c4 ? t2i : z1i;
        bool c5 = plt(w2d, w2i, u2d, u2i);
        float r2d = c5 ? w2d : u2d; int r2i = c5 ? w2i : u2i;
        d0 = m0d; i0 = m0i; d1 = r1d; i1 = r1i; d2 = r2d; i2 = r2i;
    }

    float w0 = 1.0f / addrn(d0, 1e-8f);
    float w1 = 1.0f / addrn(d1, 1e-8f);
    float w2 = 1.0f / addrn(d2, 1e-8f);
    float wsum = addrn(addrn(w0, w1), w2);
    w0 = w0 / wsum; w1 = w1 / wsum; w2 = w2 / wsum;

    // ---- per-lane argmin over m = l, l+64, ...; butterfly lexicographic min
    float dm = 1e30f; int im = 0;
#pragma unroll 4
    for (int t = 0; t < M_ / 64; t++) {
        int m = t * 64 + l;
        float4 f = *(const float4*)(fb + (size_t)m * 4);
        float cn = norm3(f.y, f.z, f.w);
        float dot = addrn(addrn(mulrn(qx, f.y), mulrn(qy, f.z)), mulrn(qz, f.w));
        float d = subrn(addrn(qn, cn), mulrn(2.0f, dot));
        if (d < dm) { dm = d; im = m; }
    }
#pragma unroll
    for (int off = 1; off < 64; off <<= 1) {
        float ed = __shfl_xor(dm, off); int ei = __shfl_xor(im, off);
        if (plt(ed, ei, dm, im)) { dm = ed; im = ei; }
    }

    // ---- assembly: XT[j][128..383] interp (lane l -> 4 channels), feature+pad
    size_t j = (size_t)b * N_ + n;
    ushort_t* xr = XT + j * KP0;
    const float* r0 = p2t + (size_t)b * S_ * D2_ + (size_t)i0 * D2_;
    const float* r1 = p2t + (size_t)b * S_ * D2_ + (size_t)i1 * D2_;
    const float* r2 = p2t + (size_t)b * S_ * D2_ + (size_t)i2 * D2_;
    {
        int c = l * 4;
        float4 a = *(const float4*)(r0 + c);
        float4 bb = *(const float4*)(r1 + c);
        float4 cc = *(const float4*)(r2 + c);
        ushort_t tmp[4];
        tmp[0] = f2bf(addrn(addrn(mulrn(a.x, w0), mulrn(bb.x, w1)), mulrn(cc.x, w2)));
        tmp[1] = f2bf(addrn(addrn(mulrn(a.y, w0), mulrn(bb.y, w1)), mulrn(cc.y, w2)));
        tmp[2] = f2bf(addrn(addrn(mulrn(a.z, w0), mulrn(bb.z, w1)), mulrn(cc.z, w2)));
        tmp[3] = f2bf(addrn(addrn(mulrn(a.w, w0), mulrn(bb.w, w1)), mulrn(cc.w, w2)));
        *(uint2*)&xr[D1_ + c] = *(uint2*)tmp;
    }
    if (l < 8) {
        uint2 v = {0u, 0u};
        if (l == 0) {
            float4 nf = *(const float4*)(fb + (size_t)im * 4);
            ushort_t tmp[4] = {f2bf(nf.x), f2bf(nf.y), f2bf(nf.z), f2bf(nf.w)};
            v = *(uint2*)tmp;
        }
        *(uint2*)&xr[384 + l * 4] = v;
    }
}

// ---------------------------------------------------------------------------
// bf16 MFMA GEMM: T[j][o] = X[j][:]·W[o][:] + bias[o], fused BN-stat atomics.
__global__ __launch_bounds__(256) void k_gemm(const ushort_t* __restrict__ Xb,
                                              const ushort_t* __restrict__ Wb,
                                              const float* __restrict__ bias,
                                              ushort_t* __restrict__ T,
                                              float* __restrict__ gsum,
                                              float* __restrict__ gsq,
                                              int Kt, int Nout) {
    __shared__ ushort_t sA[2][128 * 32];
    __shared__ ushort_t sB[2][128 * 32];
    __shared__ float redS[128][2], redQ[128][2];

    int tid = threadIdx.x;
    int l = tid & 63;
    int w = tid >> 6;
    int wr = w >> 1, wc = w & 1;
    int j0 = blockIdx.x * 128, o0 = blockIdx.y * 128;

    f32x4 acc[4][4] = {};
    int nt = Kt >> 5;

    auto stage = [&](int buf, int k0) {
#pragma unroll
        for (int e = 0; e < 2; ++e) {
            int i = e * 256 + tid;
            int row = i >> 2;
            int g = (i & 3) ^ ((row >> 1) & 3);   // pre-swizzled source chunk
            const ushort_t* ga = Xb + (size_t)(j0 + row) * Kt + k0 + g * 8;
            __builtin_amdgcn_global_load_lds(
                (const __attribute__((address_space(1))) void*)ga,
                (__attribute__((address_space(3))) void*)&sA[buf][i * 8], 16, 0, 0);
            const ushort_t* gb = Wb + (size_t)(o0 + row) * Kt + k0 + g * 8;
            __builtin_amdgcn_global_load_lds(
                (const __attribute__((address_space(1))) void*)gb,
                (__attribute__((address_space(3))) void*)&sB[buf][i * 8], 16, 0, 0);
        }
    };

    stage(0, 0);
    __syncthreads();

    for (int t = 0; t < nt; ++t) {
        int cur = t & 1;
        if (t + 1 < nt) stage(cur ^ 1, (t + 1) << 5);

        bf16x8 av[4], bv[4];
#pragma unroll
        for (int mi = 0; mi < 4; ++mi) {
            int r = wr * 64 + mi * 16 + (l & 15);
            int sl = (l >> 4) ^ ((r >> 1) & 3);
            av[mi] = *(const bf16x8*)&sA[cur][r * 32 + sl * 8];
        }
#pragma unroll
        for (int ni = 0; ni < 4; ++ni) {
            int r = wc * 64 + ni * 16 + (l & 15);
            int sl = (l >> 4) ^ ((r >> 1) & 3);
            bv[ni] = *(const bf16x8*)&sB[cur][r * 32 + sl * 8];
        }
#pragma unroll
        for (int mi = 0; mi < 4; ++mi)
#pragma unroll
            for (int ni = 0; ni < 4; ++ni)
                acc[mi][ni] = __builtin_amdgcn_mfma_f32_16x16x32_bf16(av[mi], bv[ni],
                                                                      acc[mi][ni], 0, 0, 0);
        __syncthreads();
    }

    float csum[4], csq[4];
#pragma unroll
    for (int ni = 0; ni < 4; ++ni) { csum[ni] = 0.f; csq[ni] = 0.f; }

#pragma unroll
    for (int ni = 0; ni < 4; ++ni) {
        int o = o0 + wc * 64 + ni * 16 + (l & 15);
        float bi = bias[o];
#pragma unroll
        for (int mi = 0; mi < 4; ++mi) {
            int jb = j0 + wr * 64 + mi * 16 + (l >> 4) * 4;
#pragma unroll
            for (int r = 0; r < 4; ++r) {
                float v = acc[mi][ni][r] + bi;
                csum[ni] += v;
                csq[ni] += v * v;
                T[(size_t)(jb + r) * Nout + o] = f2bf(v);
            }
        }
    }

#pragma unroll
    for (int ni = 0; ni < 4; ++ni) {
        float s = csum[ni], q = csq[ni];
        s += __shfl_xor(s, 16); s += __shfl_xor(s, 32);
        q += __shfl_xor(q, 16); q += __shfl_xor(q, 32);
        if ((l & 48) == 0) {
            redS[wc * 64 + ni * 16 + (l & 15)][wr] = s;
            redQ[wc * 64 + ni * 16 + (l & 15)][wr] = q;
        }
    }
    __syncthreads();
    if (tid < 128) {
        atomicAdd(&gsum[o0 + tid], redS[tid][0] + redS[tid][1]);
        atomicAdd(&gsq[o0 + tid], redQ[tid][0] + redQ[tid][1]);
    }
}

// ---------------------------------------------------------------------------
__global__ void k_affine(const float* __restrict__ gsum, const float* __restrict__ gsq,
                         const float* __restrict__ g, const float* __restrict__ be,
                         float* __restrict__ A, float* __restrict__ S, int C) {
    int o = blockIdx.x * 256 + threadIdx.x;
    if (o >= C) return;
    float mean = gsum[o] / (float)J_;
    float var = gsq[o] / (float)J_ - mean * mean;
    float a = g[o] * rsqrtf(var + BN_EPS);
    A[o] = a;
    S[o] = be[o] - a * mean;
}

// ---------------------------------------------------------------------------
// In-place BN+ReLU on T [J][512] bf16 (channel = col = idx & 511)
__global__ __launch_bounds__(256) void k_norm(ushort_t* __restrict__ T,
                                              const float* __restrict__ A,
                                              const float* __restrict__ S) {
    size_t idx = ((size_t)blockIdx.x * 256 + threadIdx.x) * 8;
    int o = (int)(idx & 511);
    uint4 v = *(uint4*)&T[idx];
    ushort_t* pu = (ushort_t*)&v;
#pragma unroll
    for (int i = 0; i < 8; i++) {
        float f = bf2f(pu[i]);
        f = fmaxf(A[o + i] * f + S[o + i], 0.f);
        pu[i] = f2bf(f);
    }
    *(uint4*)&T[idx] = v;
}

// ---------------------------------------------------------------------------
// T2 [J][256] bf16 + BN affine + ReLU -> out [B][256][N] fp32 (transpose)
__global__ __launch_bounds__(256) void k_final(const ushort_t* __restrict__ T2,
                                               const float* __restrict__ A,
                                               const float* __restrict__ S,
                                               float* __restrict__ out) {
    __shared__ float tile[64][65];
    int tid = threadIdx.x;
    int jb = blockIdx.z * N_ + blockIdx.x * 64;
    int o0 = blockIdx.y * 64;

    int r = tid >> 2, cq = (tid & 3) * 16;
    uint4 v = *(const uint4*)&T2[(size_t)(jb + r) * 256 + o0 + cq];
    ushort_t* pu = (ushort_t*)&v;
#pragma unroll
    for (int i = 0; i < 8; i++) {
        int o = o0 + cq + i;
        tile[r][cq + i] = fmaxf(A[o] * bf2f(pu[i]) + S[o], 0.f);
    }
    uint4 v2 = *(const uint4*)&T2[(size_t)(jb + r) * 256 + o0 + cq + 8];
    pu = (ushort_t*)&v2;
#pragma unroll
    for (int i = 0; i < 8; i++) {
        int o = o0 + cq + 8 + i;
        tile[r][cq + 8 + i] = fmaxf(A[o] * bf2f(pu[i]) + S[o], 0.f);
    }
    __syncthreads();

    int ro = tid >> 2, jq = (tid & 3) * 16;
    float* orow = out + ((size_t)blockIdx.z * 256 + o0 + ro) * N_ + blockIdx.x * 64 + jq;
#pragma unroll
    for (int h = 0; h < 4; h++) {
        float4 ov = {tile[jq + h * 4 + 0][ro], tile[jq + h * 4 + 1][ro],
                     tile[jq + h * 4 + 2][ro], tile[jq + h * 4 + 3][ro]};
        *(float4*)(orow + h * 4) = ov;
    }
}

// ---------------------------------------------------------------------------
extern "C" void kernel_launch(void* const* d_in, const int* in_sizes, int n_in,
                              void* d_out, int out_size, void* d_ws, size_t ws_size,
                              hipStream_t stream) {
    (void)in_sizes; (void)n_in; (void)out_size; (void)ws_size;
    const float* xyz1    = (const float*)d_in[0];
    const float* xyz2    = (const float*)d_in[1];
    const float* points1 = (const float*)d_in[2];
    const float* points2 = (const float*)d_in[3];
    const float* feature = (const float*)d_in[4];
    const float* W0 = (const float*)d_in[5];
    const float* b0 = (const float*)d_in[6];
    const float* g0 = (const float*)d_in[7];
    const float* be0 = (const float*)d_in[8];
    const float* W1 = (const float*)d_in[9];
    const float* b1 = (const float*)d_in[10];
    const float* g1 = (const float*)d_in[11];
    const float* be1 = (const float*)d_in[12];
    const float* W2 = (const float*)d_in[13];
    const float* b2 = (const float*)d_in[14];
    const float* g2 = (const float*)d_in[15];
    const float* be2 = (const float*)d_in[16];

    char* ws = (char*)d_ws;
    size_t off = 0;
    auto carve = [&](size_t bytes) { char* p = ws + off; off += (bytes + 255) & ~(size_t)255; return p; };

    ushort_t* XT  = (ushort_t*)carve((size_t)J_ * KP0 * 2);
    ushort_t* T0  = (ushort_t*)carve((size_t)J_ * 512 * 2);
    ushort_t* T1  = (ushort_t*)carve((size_t)J_ * 512 * 2);
    ushort_t* T2  = (ushort_t*)carve((size_t)J_ * 256 * 2);
    float*    p2t = (float*)carve((size_t)B_ * S_ * D2_ * 4);
    ushort_t* Wb0 = (ushort_t*)carve((size_t)512 * KP0 * 2);
    ushort_t* Wb1 = (ushort_t*)carve((size_t)512 * K12 * 2);
    ushort_t* Wb2 = (ushort_t*)carve((size_t)256 * K12 * 2);
    float*    st  = (float*)carve(2560 * 4);
    float*    af  = (float*)carve(2560 * 4);
    float *gs0 = st, *gq0 = st + 512, *gs1 = st + 1024, *gq1 = st + 1536, *gs2 = st + 2048, *gq2 = st + 2304;
    float *A0 = af, *S0 = af + 512, *A1 = af + 1024, *S1 = af + 1536, *A2 = af + 2048, *S2 = af + 2304;

    k_zero<<<dim3(10), 256, 0, stream>>>(st, 2560);
    k_prep_w<<<dim3((512 * KP0 + 255) / 256), 256, 0, stream>>>(W0, Wb0, 512, CIN_, KP0);
    k_prep_w<<<dim3((512 * K12 + 255) / 256), 256, 0, stream>>>(W1, Wb1, 512, 512, K12);
    k_prep_w<<<dim3((256 * K12 + 255) / 256), 256, 0, stream>>>(W2, Wb2, 256, 512, K12);
    k_transpose_p2<<<dim3(S_ / 32, D2_ / 32, B_), dim3(32, 8), 0, stream>>>(points2, p2t);
    k_p1t<<<dim3(N_ / 32, B_), 256, 0, stream>>>(points1, XT);
    k_nn<<<dim3(N_ / 4, B_), 256, 0, stream>>>(xyz1, xyz2, feature, p2t, XT);

    k_gemm<<<dim3(J_ / 128, 4), 256, 0, stream>>>(XT, Wb0, b0, T0, gs0, gq0, KP0, 512);
    k_affine<<<dim3(2), 256, 0, stream>>>(gs0, gq0, g0, be0, A0, S0, 512);
    k_norm<<<dim3((int)((size_t)J_ * 512 / 8 / 256)), 256, 0, stream>>>(T0, A0, S0);

    k_gemm<<<dim3(J_ / 128, 4), 256, 0, stream>>>(T0, Wb1, b1, T1, gs1, gq1, K12, 512);
    k_affine<<<dim3(2), 256, 0, stream>>>(gs1, gq1, g1, be1, A1, S1, 512);
    k_norm<<<dim3((int)((size_t)J_ * 512 / 8 / 256)), 256, 0, stream>>>(T1, A1, S1);

    k_gemm<<<dim3(J_ / 128, 2), 256, 0, stream>>>(T1, Wb2, b2, T2, gs2, gq2, K12, 256);
    k_affine<<<dim3(1), 256, 0, stream>>>(gs2, gq2, g2, be2, A2, S2, 256);

    k_final<<<dim3(N_ / 64, 4, B_), 256, 0, stream>>>(T2, A2, S2, (float*)d_out);
}

// Round 6
// 226.818 us; speedup vs baseline: 3.1371x; 1.0586x over previous
//
#include <hip/hip_runtime.h>

#define B_   8
#define N_   4096
#define S_   1024
#define M_   2048
#define D1_  128
#define D2_  256
#define CIN_ 388
#define KP0  416          // K of layer0, padded to 13*32
#define K12  512          // K of layers 1,2
#define J_   (B_ * N_)    // 32768
#define SS   (S_ / 8)     // 128 candidates per eighth
#define MM   (M_ / 8)     // 256 keypoints per eighth
#define BN_EPS 1e-5f

typedef __bf16 bf16x8 __attribute__((ext_vector_type(8)));
typedef float  f32x4  __attribute__((ext_vector_type(4)));
typedef unsigned short ushort_t;

__device__ __forceinline__ float mulrn(float a, float b) { return __fmul_rn(a, b); }
__device__ __forceinline__ float addrn(float a, float b) { return __fadd_rn(a, b); }
__device__ __forceinline__ float subrn(float a, float b) { return __fsub_rn(a, b); }
__device__ __forceinline__ float norm3(float x, float y, float z) {
    return addrn(addrn(mulrn(x, x), mulrn(y, y)), mulrn(z, z));
}
__device__ __forceinline__ ushort_t f2bf(float f) {  // RNE
    unsigned int u = __float_as_uint(f);
    return (ushort_t)((u + 0x7FFFu + ((u >> 16) & 1u)) >> 16);
}
__device__ __forceinline__ float bf2f(ushort_t u) {
    return __uint_as_float(((unsigned int)u) << 16);
}
// lexicographic (d, idx) compare — reproduces stable top-k tie-breaking
__device__ __forceinline__ bool plt(float da, int ia, float db, int ib) {
    return (da < db) || (da == db && ia < ib);
}

// ---------------------------------------------------------------------------
// points2 [B][D2][S] -> p2t [B][S][D2]  (fp32, feeds exact interp math)
__global__ __launch_bounds__(256) void k_transpose_p2(const float* __restrict__ p2,
                                                      float* __restrict__ p2t) {
    __shared__ float tile[32][33];
    int b = blockIdx.z;
    int s0 = blockIdx.x * 32, c0 = blockIdx.y * 32;
    int tx = threadIdx.x, ty = threadIdx.y;  // 32 x 8
#pragma unroll
    for (int i = 0; i < 4; i++)
        tile[ty + i * 8][tx] = p2[(size_t)b * D2_ * S_ + (size_t)(c0 + ty + i * 8) * S_ + s0 + tx];
    __syncthreads();
#pragma unroll
    for (int i = 0; i < 4; i++)
        p2t[(size_t)b * S_ * D2_ + (size_t)(s0 + ty + i * 8) * D2_ + c0 + tx] = tile[tx][ty + i * 8];
}

// ---------------------------------------------------------------------------
// W [O][C] fp32 -> Wb [O][Kp] bf16, zero-padded cols (already k-contiguous)
__global__ __launch_bounds__(256) void k_prep_w(const float* __restrict__ W,
                                                ushort_t* __restrict__ Wb, int O, int C, int Kp) {
    int i = blockIdx.x * 256 + threadIdx.x;
    if (i >= O * Kp) return;
    int o = i / Kp, k = i - o * Kp;
    Wb[i] = (k < C) ? f2bf(W[(size_t)o * C + k]) : (ushort_t)0;
}

// ---------------------------------------------------------------------------
__global__ void k_zero(float* p, int n) {
    int i = blockIdx.x * 256 + threadIdx.x;
    if (i < n) p[i] = 0.f;
}

// ---------------------------------------------------------------------------
// points1 [B][D1][N] fp32 -> XT[j][0:128] bf16 (LDS tile transpose)
__global__ __launch_bounds__(256) void k_p1t(const float* __restrict__ p1,
                                             ushort_t* __restrict__ XT) {
    __shared__ ushort_t tile[32][132];
    int b = blockIdx.y;
    int n0 = blockIdx.x * 32;
    int t = threadIdx.x;

    {
        int nl = t & 31, cq = t >> 5;
#pragma unroll
        for (int k = 0; k < 16; k++) {
            int c = cq * 16 + k;
            tile[nl][c] = f2bf(p1[(size_t)b * D1_ * N_ + (size_t)c * N_ + n0 + nl]);
        }
    }
    __syncthreads();
    {
        int nl = t >> 3, sub = t & 7;
        size_t j = (size_t)b * N_ + n0 + nl;
#pragma unroll
        for (int k = 0; k < 4; k++) {
            int chunk = k * 8 + sub;
            *(uint2*)&XT[j * KP0 + chunk * 4] = *(const uint2*)&tile[nl][chunk * 4];
        }
    }
}

// ---------------------------------------------------------------------------
// Scan phase: one THREAD per query, one candidate-EIGHTH per block.
// Candidates (+hoisted norms) live in LDS, read wave-uniform (broadcast).
// Per-eighth top-3 (strict <, ascending index) + per-eighth argmin.
// Out layout per (j, e): {d0,d1,d2,dm, i0,i1,i2,im} (ints as bit-cast floats).
__global__ __launch_bounds__(512) void k_scan(const float* __restrict__ xyz1,
                                              const float* __restrict__ xyz2,
                                              const float* __restrict__ feature,
                                              float* __restrict__ outp) {
    __shared__ float4 sL[SS];
    __shared__ float4 fL[MM];
    int tid = threadIdx.x;
    int e = blockIdx.y;
    int j = blockIdx.x * 512 + tid;
    int b = blockIdx.x >> 3;           // 8 blocks.x per batch (4096/512)
    int n = j & (N_ - 1);

    for (int i = tid; i < SS + MM; i += 512) {
        if (i < SS) {
            int s = e * SS + i;
            float x = xyz2[(size_t)b * 3 * S_ + s];
            float y = xyz2[(size_t)b * 3 * S_ + S_ + s];
            float z = xyz2[(size_t)b * 3 * S_ + 2 * S_ + s];
            sL[i] = make_float4(x, y, z, norm3(x, y, z));
        } else {
            int m = e * MM + (i - SS);
            float4 f = *(const float4*)(feature + (size_t)b * M_ * 4 + (size_t)m * 4);
            fL[i - SS] = make_float4(f.y, f.z, f.w, norm3(f.y, f.z, f.w));
        }
    }
    __syncthreads();

    float qx = xyz1[(size_t)b * 3 * N_ + n];
    float qy = xyz1[(size_t)b * 3 * N_ + N_ + n];
    float qz = xyz1[(size_t)b * 3 * N_ + 2 * N_ + n];
    float qn = norm3(qx, qy, qz);

    float d0 = 1e30f, d1 = 1e30f, d2 = 1e30f;
    int i0 = 0, i1 = 0, i2 = 0;
#pragma unroll 4
    for (int i = 0; i < SS; i++) {
        float4 c = sL[i];
        float dot = addrn(addrn(mulrn(qx, c.x), mulrn(qy, c.y)), mulrn(qz, c.z));
        float d = subrn(addrn(qn, c.w), mulrn(2.0f, dot));
        int s = e * SS + i;
        bool l0 = d < d0, l1 = d < d1, l2 = d < d2;
        d2 = l1 ? d1 : (l2 ? d : d2);  i2 = l1 ? i1 : (l2 ? s : i2);
        d1 = l0 ? d0 : (l1 ? d : d1);  i1 = l0 ? i0 : (l1 ? s : i1);
        d0 = l0 ? d  : d0;             i0 = l0 ? s  : i0;
    }

    float dm = 1e30f; int im = 0;
#pragma unroll 4
    for (int i = 0; i < MM; i++) {
        float4 c = fL[i];
        float dot = addrn(addrn(mulrn(qx, c.x), mulrn(qy, c.y)), mulrn(qz, c.z));
        float d = subrn(addrn(qn, c.w), mulrn(2.0f, dot));
        if (d < dm) { dm = d; im = e * MM + i; }
    }

    float* o = outp + ((size_t)j * 8 + e) * 8;
    float4 v0 = {d0, d1, d2, dm};
    float4 v1 = {__int_as_float(i0), __int_as_float(i1), __int_as_float(i2), __int_as_float(im)};
    *(float4*)o = v0;
    *(float4*)(o + 4) = v1;
}

// ---------------------------------------------------------------------------
// Merge + assembly: one WAVE per query. Lanes 0-7 hold the 8 eighth-results;
// 3-step lexicographic butterfly merge (validated network), broadcast, then
// wave-parallel interp assembly into XT[j][128..415].
__global__ __launch_bounds__(256) void k_nn2(const float* __restrict__ feature,
                                             const float* __restrict__ p2t,
                                             const float* __restrict__ outp,
                                             ushort_t* __restrict__ XT) {
    int bq = blockIdx.y;
    int wid = threadIdx.x >> 6;
    int l = threadIdx.x & 63;
    int n = blockIdx.x * 4 + wid;
    size_t j = (size_t)bq * N_ + n;
    const float* fb = feature + (size_t)bq * M_ * 4;

    float d0 = 1e30f, d1 = 1e30f, d2 = 1e30f, dm = 1e30f;
    int i0 = 0, i1 = 0, i2 = 0, im = 0;
    if (l < 8) {
        const float* o = outp + (j * 8 + l) * 8;
        float4 a = *(const float4*)o;
        float4 bi = *(const float4*)(o + 4);
        d0 = a.x; d1 = a.y; d2 = a.z; dm = a.w;
        i0 = __float_as_int(bi.x); i1 = __float_as_int(bi.y);
        i2 = __float_as_int(bi.z); im = __float_as_int(bi.w);
    }

#pragma unroll
    for (int off = 1; off < 8; off <<= 1) {
        float e0 = __shfl_xor(d0, off), e1 = __shfl_xor(d1, off), e2 = __shfl_xor(d2, off);
        int   f0 = __shfl_xor(i0, off), f1 = __shfl_xor(i1, off), f2 = __shfl_xor(i2, off);
        bool c0 = plt(e0, f0, d0, i0);
        float m0d = c0 ? e0 : d0; int m0i = c0 ? f0 : i0;
        float x0d = c0 ? d0 : e0; int x0i = c0 ? i0 : f0;
        bool c1 = plt(e1, f1, d1, i1);
        float n1d = c1 ? e1 : d1; int n1i = c1 ? f1 : i1;
        float z1d = c1 ? d1 : e1; int z1i = c1 ? i1 : f1;
        bool c2 = plt(e2, f2, d2, i2);
        float w2d = c2 ? e2 : d2; int w2i = c2 ? f2 : i2;
        bool c3 = plt(n1d, n1i, x0d, x0i);
        float r1d = c3 ? n1d : x0d; int r1i = c3 ? n1i : x0i;
        float t2d = c3 ? x0d : n1d; int t2i = c3 ? x0i : n1i;
        bool c4 = plt(t2d, t2i, z1d, z1i);
        float u2d = c4 ? t2d : z1d; int u2i = c4 ? t2i : z1i;
        bool c5 = plt(w2d, w2i, u2d, u2i);
        float r2d = c5 ? w2d : u2d; int r2i = c5 ? w2i : u2i;
        d0 = m0d; i0 = m0i; d1 = r1d; i1 = r1i; d2 = r2d; i2 = r2i;

        float ed = __shfl_xor(dm, off); int ei = __shfl_xor(im, off);
        if (plt(ed, ei, dm, im)) { dm = ed; im = ei; }
    }

    // broadcast merged result from lane 0 to all 64 lanes
    d0 = __shfl(d0, 0); d1 = __shfl(d1, 0); d2 = __shfl(d2, 0);
    i0 = __shfl(i0, 0); i1 = __shfl(i1, 0); i2 = __shfl(i2, 0);
    im = __shfl(im, 0);

    float w0 = 1.0f / addrn(d0, 1e-8f);
    float w1 = 1.0f / addrn(d1, 1e-8f);
    float w2 = 1.0f / addrn(d2, 1e-8f);
    float wsum = addrn(addrn(w0, w1), w2);
    w0 = w0 / wsum; w1 = w1 / wsum; w2 = w2 / wsum;

    ushort_t* xr = XT + j * KP0;
    const float* r0 = p2t + (size_t)bq * S_ * D2_ + (size_t)i0 * D2_;
    const float* r1 = p2t + (size_t)bq * S_ * D2_ + (size_t)i1 * D2_;
    const float* r2 = p2t + (size_t)bq * S_ * D2_ + (size_t)i2 * D2_;
    {
        int c = l * 4;
        float4 a = *(const float4*)(r0 + c);
        float4 bb = *(const float4*)(r1 + c);
        float4 cc = *(const float4*)(r2 + c);
        ushort_t tmp[4];
        tmp[0] = f2bf(addrn(addrn(mulrn(a.x, w0), mulrn(bb.x, w1)), mulrn(cc.x, w2)));
        tmp[1] = f2bf(addrn(addrn(mulrn(a.y, w0), mulrn(bb.y, w1)), mulrn(cc.y, w2)));
        tmp[2] = f2bf(addrn(addrn(mulrn(a.z, w0), mulrn(bb.z, w1)), mulrn(cc.z, w2)));
        tmp[3] = f2bf(addrn(addrn(mulrn(a.w, w0), mulrn(bb.w, w1)), mulrn(cc.w, w2)));
        *(uint2*)&xr[D1_ + c] = *(uint2*)tmp;
    }
    if (l < 8) {
        uint2 v = {0u, 0u};
        if (l == 0) {
            float4 nf = *(const float4*)(fb + (size_t)im * 4);
            ushort_t tmp[4] = {f2bf(nf.x), f2bf(nf.y), f2bf(nf.z), f2bf(nf.w)};
            v = *(uint2*)tmp;
        }
        *(uint2*)&xr[384 + l * 4] = v;
    }
}

// ---------------------------------------------------------------------------
// bf16 MFMA GEMM: T[j][o] = X[j][:]·W[o][:] + bias[o], fused BN-stat atomics.
__global__ __launch_bounds__(256) void k_gemm(const ushort_t* __restrict__ Xb,
                                              const ushort_t* __restrict__ Wb,
                                              const float* __restrict__ bias,
                                              ushort_t* __restrict__ T,
                                              float* __restrict__ gsum,
                                              float* __restrict__ gsq,
                                              int Kt, int Nout) {
    __shared__ ushort_t sA[2][128 * 32];
    __shared__ ushort_t sB[2][128 * 32];
    __shared__ float redS[128][2], redQ[128][2];

    int tid = threadIdx.x;
    int l = tid & 63;
    int w = tid >> 6;
    int wr = w >> 1, wc = w & 1;
    int j0 = blockIdx.x * 128, o0 = blockIdx.y * 128;

    f32x4 acc[4][4] = {};
    int nt = Kt >> 5;

    auto stage = [&](int buf, int k0) {
#pragma unroll
        for (int e = 0; e < 2; ++e) {
            int i = e * 256 + tid;
            int row = i >> 2;
            int g = (i & 3) ^ ((row >> 1) & 3);
            const ushort_t* ga = Xb + (size_t)(j0 + row) * Kt + k0 + g * 8;
            __builtin_amdgcn_global_load_lds(
                (const __attribute__((address_space(1))) void*)ga,
                (__attribute__((address_space(3))) void*)&sA[buf][i * 8], 16, 0, 0);
            const ushort_t* gb = Wb + (size_t)(o0 + row) * Kt + k0 + g * 8;
            __builtin_amdgcn_global_load_lds(
                (const __attribute__((address_space(1))) void*)gb,
                (__attribute__((address_space(3))) void*)&sB[buf][i * 8], 16, 0, 0);
        }
    };

    stage(0, 0);
    __syncthreads();

    for (int t = 0; t < nt; ++t) {
        int cur = t & 1;
        if (t + 1 < nt) stage(cur ^ 1, (t + 1) << 5);

        bf16x8 av[4], bv[4];
#pragma unroll
        for (int mi = 0; mi < 4; ++mi) {
            int r = wr * 64 + mi * 16 + (l & 15);
            int sl = (l >> 4) ^ ((r >> 1) & 3);
            av[mi] = *(const bf16x8*)&sA[cur][r * 32 + sl * 8];
        }
#pragma unroll
        for (int ni = 0; ni < 4; ++ni) {
            int r = wc * 64 + ni * 16 + (l & 15);
            int sl = (l >> 4) ^ ((r >> 1) & 3);
            bv[ni] = *(const bf16x8*)&sB[cur][r * 32 + sl * 8];
        }
#pragma unroll
        for (int mi = 0; mi < 4; ++mi)
#pragma unroll
            for (int ni = 0; ni < 4; ++ni)
                acc[mi][ni] = __builtin_amdgcn_mfma_f32_16x16x32_bf16(av[mi], bv[ni],
                                                                      acc[mi][ni], 0, 0, 0);
        __syncthreads();
    }

    float csum[4], csq[4];
#pragma unroll
    for (int ni = 0; ni < 4; ++ni) { csum[ni] = 0.f; csq[ni] = 0.f; }

#pragma unroll
    for (int ni = 0; ni < 4; ++ni) {
        int o = o0 + wc * 64 + ni * 16 + (l & 15);
        float bi = bias[o];
#pragma unroll
        for (int mi = 0; mi < 4; ++mi) {
            int jb = j0 + wr * 64 + mi * 16 + (l >> 4) * 4;
#pragma unroll
            for (int r = 0; r < 4; ++r) {
                float v = acc[mi][ni][r] + bi;
                csum[ni] += v;
                csq[ni] += v * v;
                T[(size_t)(jb + r) * Nout + o] = f2bf(v);
            }
        }
    }

#pragma unroll
    for (int ni = 0; ni < 4; ++ni) {
        float s = csum[ni], q = csq[ni];
        s += __shfl_xor(s, 16); s += __shfl_xor(s, 32);
        q += __shfl_xor(q, 16); q += __shfl_xor(q, 32);
        if ((l & 48) == 0) {
            redS[wc * 64 + ni * 16 + (l & 15)][wr] = s;
            redQ[wc * 64 + ni * 16 + (l & 15)][wr] = q;
        }
    }
    __syncthreads();
    if (tid < 128) {
        atomicAdd(&gsum[o0 + tid], redS[tid][0] + redS[tid][1]);
        atomicAdd(&gsq[o0 + tid], redQ[tid][0] + redQ[tid][1]);
    }
}

// ---------------------------------------------------------------------------
__global__ void k_affine(const float* __restrict__ gsum, const float* __restrict__ gsq,
                         const float* __restrict__ g, const float* __restrict__ be,
                         float* __restrict__ A, float* __restrict__ S, int C) {
    int o = blockIdx.x * 256 + threadIdx.x;
    if (o >= C) return;
    float mean = gsum[o] / (float)J_;
    float var = gsq[o] / (float)J_ - mean * mean;
    float a = g[o] * rsqrtf(var + BN_EPS);
    A[o] = a;
    S[o] = be[o] - a * mean;
}

// ---------------------------------------------------------------------------
// In-place BN+ReLU on T [J][512] bf16 (channel = col = idx & 511)
__global__ __launch_bounds__(256) void k_norm(ushort_t* __restrict__ T,
                                              const float* __restrict__ A,
                                              const float* __restrict__ S) {
    size_t idx = ((size_t)blockIdx.x * 256 + threadIdx.x) * 8;
    int o = (int)(idx & 511);
    uint4 v = *(uint4*)&T[idx];
    ushort_t* pu = (ushort_t*)&v;
#pragma unroll
    for (int i = 0; i < 8; i++) {
        float f = bf2f(pu[i]);
        f = fmaxf(A[o + i] * f + S[o + i], 0.f);
        pu[i] = f2bf(f);
    }
    *(uint4*)&T[idx] = v;
}

// ---------------------------------------------------------------------------
// T2 [J][256] bf16 + BN affine + ReLU -> out [B][256][N] fp32 (transpose)
__global__ __launch_bounds__(256) void k_final(const ushort_t* __restrict__ T2,
                                               const float* __restrict__ A,
                                               const float* __restrict__ S,
                                               float* __restrict__ out) {
    __shared__ float tile[64][65];
    int tid = threadIdx.x;
    int jb = blockIdx.z * N_ + blockIdx.x * 64;
    int o0 = blockIdx.y * 64;

    int r = tid >> 2, cq = (tid & 3) * 16;
    uint4 v = *(const uint4*)&T2[(size_t)(jb + r) * 256 + o0 + cq];
    ushort_t* pu = (ushort_t*)&v;
#pragma unroll
    for (int i = 0; i < 8; i++) {
        int o = o0 + cq + i;
        tile[r][cq + i] = fmaxf(A[o] * bf2f(pu[i]) + S[o], 0.f);
    }
    uint4 v2 = *(const uint4*)&T2[(size_t)(jb + r) * 256 + o0 + cq + 8];
    pu = (ushort_t*)&v2;
#pragma unroll
    for (int i = 0; i < 8; i++) {
        int o = o0 + cq + 8 + i;
        tile[r][cq + 8 + i] = fmaxf(A[o] * bf2f(pu[i]) + S[o], 0.f);
    }
    __syncthreads();

    int ro = tid >> 2, jq = (tid & 3) * 16;
    float* orow = out + ((size_t)blockIdx.z * 256 + o0 + ro) * N_ + blockIdx.x * 64 + jq;
#pragma unroll
    for (int h = 0; h < 4; h++) {
        float4 ov = {tile[jq + h * 4 + 0][ro], tile[jq + h * 4 + 1][ro],
                     tile[jq + h * 4 + 2][ro], tile[jq + h * 4 + 3][ro]};
        *(float4*)(orow + h * 4) = ov;
    }
}

// ---------------------------------------------------------------------------
extern "C" void kernel_launch(void* const* d_in, const int* in_sizes, int n_in,
                              void* d_out, int out_size, void* d_ws, size_t ws_size,
                              hipStream_t stream) {
    (void)in_sizes; (void)n_in; (void)out_size; (void)ws_size;
    const float* xyz1    = (const float*)d_in[0];
    const float* xyz2    = (const float*)d_in[1];
    const float* points1 = (const float*)d_in[2];
    const float* points2 = (const float*)d_in[3];
    const float* feature = (const float*)d_in[4];
    const float* W0 = (const float*)d_in[5];
    const float* b0 = (const float*)d_in[6];
    const float* g0 = (const float*)d_in[7];
    const float* be0 = (const float*)d_in[8];
    const float* W1 = (const float*)d_in[9];
    const float* b1 = (const float*)d_in[10];
    const float* g1 = (const float*)d_in[11];
    const float* be1 = (const float*)d_in[12];
    const float* W2 = (const float*)d_in[13];
    const float* b2 = (const float*)d_in[14];
    const float* g2 = (const float*)d_in[15];
    const float* be2 = (const float*)d_in[16];

    char* ws = (char*)d_ws;
    size_t off = 0;
    auto carve = [&](size_t bytes) { char* p = ws + off; off += (bytes + 255) & ~(size_t)255; return p; };

    ushort_t* XT  = (ushort_t*)carve((size_t)J_ * KP0 * 2);
    ushort_t* T0  = (ushort_t*)carve((size_t)J_ * 512 * 2);
    ushort_t* T1  = (ushort_t*)carve((size_t)J_ * 512 * 2);
    ushort_t* T2  = (ushort_t*)carve((size_t)J_ * 256 * 2);
    float*    p2t = (float*)carve((size_t)B_ * S_ * D2_ * 4);
    float*    nnp = (float*)carve((size_t)J_ * 64 * 4);       // 8 eighths x 8 words
    ushort_t* Wb0 = (ushort_t*)carve((size_t)512 * KP0 * 2);
    ushort_t* Wb1 = (ushort_t*)carve((size_t)512 * K12 * 2);
    ushort_t* Wb2 = (ushort_t*)carve((size_t)256 * K12 * 2);
    float*    st  = (float*)carve(2560 * 4);
    float*    af  = (float*)carve(2560 * 4);
    float *gs0 = st, *gq0 = st + 512, *gs1 = st + 1024, *gq1 = st + 1536, *gs2 = st + 2048, *gq2 = st + 2304;
    float *A0 = af, *S0 = af + 512, *A1 = af + 1024, *S1 = af + 1536, *A2 = af + 2048, *S2 = af + 2304;

    k_zero<<<dim3(10), 256, 0, stream>>>(st, 2560);
    k_prep_w<<<dim3((512 * KP0 + 255) / 256), 256, 0, stream>>>(W0, Wb0, 512, CIN_, KP0);
    k_prep_w<<<dim3((512 * K12 + 255) / 256), 256, 0, stream>>>(W1, Wb1, 512, 512, K12);
    k_prep_w<<<dim3((256 * K12 + 255) / 256), 256, 0, stream>>>(W2, Wb2, 256, 512, K12);
    k_transpose_p2<<<dim3(S_ / 32, D2_ / 32, B_), dim3(32, 8), 0, stream>>>(points2, p2t);
    k_p1t<<<dim3(N_ / 32, B_), 256, 0, stream>>>(points1, XT);
    k_scan<<<dim3(J_ / 512, 8), 512, 0, stream>>>(xyz1, xyz2, feature, nnp);
    k_nn2<<<dim3(N_ / 4, B_), 256, 0, stream>>>(feature, p2t, nnp, XT);

    k_gemm<<<dim3(J_ / 128, 4), 256, 0, stream>>>(XT, Wb0, b0, T0, gs0, gq0, KP0, 512);
    k_affine<<<dim3(2), 256, 0, stream>>>(gs0, gq0, g0, be0, A0, S0, 512);
    k_norm<<<dim3((int)((size_t)J_ * 512 / 8 / 256)), 256, 0, stream>>>(T0, A0, S0);

    k_gemm<<<dim3(J_ / 128, 4), 256, 0, stream>>>(T0, Wb1, b1, T1, gs1, gq1, K12, 512);
    k_affine<<<dim3(2), 256, 0, stream>>>(gs1, gq1, g1, be1, A1, S1, 512);
    k_norm<<<dim3((int)((size_t)J_ * 512 / 8 / 256)), 256, 0, stream>>>(T1, A1, S1);

    k_gemm<<<dim3(J_ / 128, 2), 256, 0, stream>>>(T1, Wb2, b2, T2, gs2, gq2, K12, 256);
    k_affine<<<dim3(1), 256, 0, stream>>>(gs2, gq2, g2, be2, A2, S2, 256);

    k_final<<<dim3(N_ / 64, 4, B_), 256, 0, stream>>>(T2, A2, S2, (float*)d_out);
}

// Round 7
// 219.637 us; speedup vs baseline: 3.2397x; 1.0327x over previous
//
#include <hip/hip_runtime.h>

#define B_   8
#define N_   4096
#define S_   1024
#define M_   2048
#define D1_  128
#define D2_  256
#define CIN_ 388
#define KP0  416          // K of layer0, padded to 13*32
#define K12  512          // K of layers 1,2
#define J_   (B_ * N_)    // 32768
#define SS   (S_ / 8)     // 128 candidates per eighth
#define MM   (M_ / 8)     // 256 keypoints per eighth
#define BN_EPS 1e-5f

typedef __bf16 bf16x8 __attribute__((ext_vector_type(8)));
typedef float  f32x4  __attribute__((ext_vector_type(4)));
typedef unsigned short ushort_t;

__device__ __forceinline__ float mulrn(float a, float b) { return __fmul_rn(a, b); }
__device__ __forceinline__ float addrn(float a, float b) { return __fadd_rn(a, b); }
__device__ __forceinline__ float subrn(float a, float b) { return __fsub_rn(a, b); }
__device__ __forceinline__ float norm3(float x, float y, float z) {
    return addrn(addrn(mulrn(x, x), mulrn(y, y)), mulrn(z, z));
}
__device__ __forceinline__ ushort_t f2bf(float f) {  // RNE
    unsigned int u = __float_as_uint(f);
    return (ushort_t)((u + 0x7FFFu + ((u >> 16) & 1u)) >> 16);
}
__device__ __forceinline__ float bf2f(ushort_t u) {
    return __uint_as_float(((unsigned int)u) << 16);
}
// lexicographic (d, idx) compare — reproduces stable top-k tie-breaking
__device__ __forceinline__ bool plt(float da, int ia, float db, int ib) {
    return (da < db) || (da == db && ia < ib);
}

// ---------------------------------------------------------------------------
// points2 [B][D2][S] -> p2t [B][S][D2]  (fp32, feeds exact interp math)
__global__ __launch_bounds__(256) void k_transpose_p2(const float* __restrict__ p2,
                                                      float* __restrict__ p2t) {
    __shared__ float tile[32][33];
    int b = blockIdx.z;
    int s0 = blockIdx.x * 32, c0 = blockIdx.y * 32;
    int tx = threadIdx.x, ty = threadIdx.y;  // 32 x 8
#pragma unroll
    for (int i = 0; i < 4; i++)
        tile[ty + i * 8][tx] = p2[(size_t)b * D2_ * S_ + (size_t)(c0 + ty + i * 8) * S_ + s0 + tx];
    __syncthreads();
#pragma unroll
    for (int i = 0; i < 4; i++)
        p2t[(size_t)b * S_ * D2_ + (size_t)(s0 + ty + i * 8) * D2_ + c0 + tx] = tile[tx][ty + i * 8];
}

// ---------------------------------------------------------------------------
// W [O][C] fp32 -> Wb [O][Kp] bf16, zero-padded cols (already k-contiguous)
__global__ __launch_bounds__(256) void k_prep_w(const float* __restrict__ W,
                                                ushort_t* __restrict__ Wb, int O, int C, int Kp) {
    int i = blockIdx.x * 256 + threadIdx.x;
    if (i >= O * Kp) return;
    int o = i / Kp, k = i - o * Kp;
    Wb[i] = (k < C) ? f2bf(W[(size_t)o * C + k]) : (ushort_t)0;
}

// ---------------------------------------------------------------------------
__global__ void k_zero(float* p, int n) {
    int i = blockIdx.x * 256 + threadIdx.x;
    if (i < n) p[i] = 0.f;
}

// ---------------------------------------------------------------------------
// points1 [B][D1][N] fp32 -> XT[j][0:128] bf16 (LDS tile transpose)
__global__ __launch_bounds__(256) void k_p1t(const float* __restrict__ p1,
                                             ushort_t* __restrict__ XT) {
    __shared__ ushort_t tile[32][132];
    int b = blockIdx.y;
    int n0 = blockIdx.x * 32;
    int t = threadIdx.x;

    {
        int nl = t & 31, cq = t >> 5;
#pragma unroll
        for (int k = 0; k < 16; k++) {
            int c = cq * 16 + k;
            tile[nl][c] = f2bf(p1[(size_t)b * D1_ * N_ + (size_t)c * N_ + n0 + nl]);
        }
    }
    __syncthreads();
    {
        int nl = t >> 3, sub = t & 7;
        size_t j = (size_t)b * N_ + n0 + nl;
#pragma unroll
        for (int k = 0; k < 4; k++) {
            int chunk = k * 8 + sub;
            *(uint2*)&XT[j * KP0 + chunk * 4] = *(const uint2*)&tile[nl][chunk * 4];
        }
    }
}

// ---------------------------------------------------------------------------
// Scan phase: one THREAD per query, one candidate-EIGHTH per block.
__global__ __launch_bounds__(512) void k_scan(const float* __restrict__ xyz1,
                                              const float* __restrict__ xyz2,
                                              const float* __restrict__ feature,
                                              float* __restrict__ outp) {
    __shared__ float4 sL[SS];
    __shared__ float4 fL[MM];
    int tid = threadIdx.x;
    int e = blockIdx.y;
    int j = blockIdx.x * 512 + tid;
    int b = blockIdx.x >> 3;           // 8 blocks.x per batch (4096/512)
    int n = j & (N_ - 1);

    for (int i = tid; i < SS + MM; i += 512) {
        if (i < SS) {
            int s = e * SS + i;
            float x = xyz2[(size_t)b * 3 * S_ + s];
            float y = xyz2[(size_t)b * 3 * S_ + S_ + s];
            float z = xyz2[(size_t)b * 3 * S_ + 2 * S_ + s];
            sL[i] = make_float4(x, y, z, norm3(x, y, z));
        } else {
            int m = e * MM + (i - SS);
            float4 f = *(const float4*)(feature + (size_t)b * M_ * 4 + (size_t)m * 4);
            fL[i - SS] = make_float4(f.y, f.z, f.w, norm3(f.y, f.z, f.w));
        }
    }
    __syncthreads();

    float qx = xyz1[(size_t)b * 3 * N_ + n];
    float qy = xyz1[(size_t)b * 3 * N_ + N_ + n];
    float qz = xyz1[(size_t)b * 3 * N_ + 2 * N_ + n];
    float qn = norm3(qx, qy, qz);

    float d0 = 1e30f, d1 = 1e30f, d2 = 1e30f;
    int i0 = 0, i1 = 0, i2 = 0;
#pragma unroll 4
    for (int i = 0; i < SS; i++) {
        float4 c = sL[i];
        float dot = addrn(addrn(mulrn(qx, c.x), mulrn(qy, c.y)), mulrn(qz, c.z));
        float d = subrn(addrn(qn, c.w), mulrn(2.0f, dot));
        int s = e * SS + i;
        bool l0 = d < d0, l1 = d < d1, l2 = d < d2;
        d2 = l1 ? d1 : (l2 ? d : d2);  i2 = l1 ? i1 : (l2 ? s : i2);
        d1 = l0 ? d0 : (l1 ? d : d1);  i1 = l0 ? i0 : (l1 ? s : i1);
        d0 = l0 ? d  : d0;             i0 = l0 ? s  : i0;
    }

    float dm = 1e30f; int im = 0;
#pragma unroll 4
    for (int i = 0; i < MM; i++) {
        float4 c = fL[i];
        float dot = addrn(addrn(mulrn(qx, c.x), mulrn(qy, c.y)), mulrn(qz, c.z));
        float d = subrn(addrn(qn, c.w), mulrn(2.0f, dot));
        if (d < dm) { dm = d; im = e * MM + i; }
    }

    float* o = outp + ((size_t)j * 8 + e) * 8;
    float4 v0 = {d0, d1, d2, dm};
    float4 v1 = {__int_as_float(i0), __int_as_float(i1), __int_as_float(i2), __int_as_float(im)};
    *(float4*)o = v0;
    *(float4*)(o + 4) = v1;
}

// ---------------------------------------------------------------------------
// Merge + assembly: one WAVE per query; 3-step lexicographic butterfly merge.
__global__ __launch_bounds__(256) void k_nn2(const float* __restrict__ feature,
                                             const float* __restrict__ p2t,
                                             const float* __restrict__ outp,
                                             ushort_t* __restrict__ XT) {
    int bq = blockIdx.y;
    int wid = threadIdx.x >> 6;
    int l = threadIdx.x & 63;
    int n = blockIdx.x * 4 + wid;
    size_t j = (size_t)bq * N_ + n;
    const float* fb = feature + (size_t)bq * M_ * 4;

    float d0 = 1e30f, d1 = 1e30f, d2 = 1e30f, dm = 1e30f;
    int i0 = 0, i1 = 0, i2 = 0, im = 0;
    if (l < 8) {
        const float* o = outp + (j * 8 + l) * 8;
        float4 a = *(const float4*)o;
        float4 bi = *(const float4*)(o + 4);
        d0 = a.x; d1 = a.y; d2 = a.z; dm = a.w;
        i0 = __float_as_int(bi.x); i1 = __float_as_int(bi.y);
        i2 = __float_as_int(bi.z); im = __float_as_int(bi.w);
    }

#pragma unroll
    for (int off = 1; off < 8; off <<= 1) {
        float e0 = __shfl_xor(d0, off), e1 = __shfl_xor(d1, off), e2 = __shfl_xor(d2, off);
        int   f0 = __shfl_xor(i0, off), f1 = __shfl_xor(i1, off), f2 = __shfl_xor(i2, off);
        bool c0 = plt(e0, f0, d0, i0);
        float m0d = c0 ? e0 : d0; int m0i = c0 ? f0 : i0;
        float x0d = c0 ? d0 : e0; int x0i = c0 ? i0 : f0;
        bool c1 = plt(e1, f1, d1, i1);
        float n1d = c1 ? e1 : d1; int n1i = c1 ? f1 : i1;
        float z1d = c1 ? d1 : e1; int z1i = c1 ? i1 : f1;
        bool c2 = plt(e2, f2, d2, i2);
        float w2d = c2 ? e2 : d2; int w2i = c2 ? f2 : i2;
        bool c3 = plt(n1d, n1i, x0d, x0i);
        float r1d = c3 ? n1d : x0d; int r1i = c3 ? n1i : x0i;
        float t2d = c3 ? x0d : n1d; int t2i = c3 ? x0i : n1i;
        bool c4 = plt(t2d, t2i, z1d, z1i);
        float u2d = c4 ? t2d : z1d; int u2i = c4 ? t2i : z1i;
        bool c5 = plt(w2d, w2i, u2d, u2i);
        float r2d = c5 ? w2d : u2d; int r2i = c5 ? w2i : u2i;
        d0 = m0d; i0 = m0i; d1 = r1d; i1 = r1i; d2 = r2d; i2 = r2i;

        float ed = __shfl_xor(dm, off); int ei = __shfl_xor(im, off);
        if (plt(ed, ei, dm, im)) { dm = ed; im = ei; }
    }

    d0 = __shfl(d0, 0); d1 = __shfl(d1, 0); d2 = __shfl(d2, 0);
    i0 = __shfl(i0, 0); i1 = __shfl(i1, 0); i2 = __shfl(i2, 0);
    im = __shfl(im, 0);

    float w0 = 1.0f / addrn(d0, 1e-8f);
    float w1 = 1.0f / addrn(d1, 1e-8f);
    float w2 = 1.0f / addrn(d2, 1e-8f);
    float wsum = addrn(addrn(w0, w1), w2);
    w0 = w0 / wsum; w1 = w1 / wsum; w2 = w2 / wsum;

    ushort_t* xr = XT + j * KP0;
    const float* r0 = p2t + (size_t)bq * S_ * D2_ + (size_t)i0 * D2_;
    const float* r1 = p2t + (size_t)bq * S_ * D2_ + (size_t)i1 * D2_;
    const float* r2 = p2t + (size_t)bq * S_ * D2_ + (size_t)i2 * D2_;
    {
        int c = l * 4;
        float4 a = *(const float4*)(r0 + c);
        float4 bb = *(const float4*)(r1 + c);
        float4 cc = *(const float4*)(r2 + c);
        ushort_t tmp[4];
        tmp[0] = f2bf(addrn(addrn(mulrn(a.x, w0), mulrn(bb.x, w1)), mulrn(cc.x, w2)));
        tmp[1] = f2bf(addrn(addrn(mulrn(a.y, w0), mulrn(bb.y, w1)), mulrn(cc.y, w2)));
        tmp[2] = f2bf(addrn(addrn(mulrn(a.z, w0), mulrn(bb.z, w1)), mulrn(cc.z, w2)));
        tmp[3] = f2bf(addrn(addrn(mulrn(a.w, w0), mulrn(bb.w, w1)), mulrn(cc.w, w2)));
        *(uint2*)&xr[D1_ + c] = *(uint2*)tmp;
    }
    if (l < 8) {
        uint2 v = {0u, 0u};
        if (l == 0) {
            float4 nf = *(const float4*)(fb + (size_t)im * 4);
            ushort_t tmp[4] = {f2bf(nf.x), f2bf(nf.y), f2bf(nf.z), f2bf(nf.w)};
            v = *(uint2*)tmp;
        }
        *(uint2*)&xr[384 + l * 4] = v;
    }
}

// ---------------------------------------------------------------------------
// bf16 MFMA GEMM: T[j][o] = X'[j][:]·W[o][:] + bias[o], fused BN-stat atomics.
// FB=true: X' = relu(bnA*X + bnS) applied during reg-staged X load (replaces
// the separate k_norm pass); W always via global_load_lds. Coalesced C-write
// through an LDS bounce tile [128][136] (272B row pad).
template<bool FB>
__global__ __launch_bounds__(256) void k_gemm(const ushort_t* __restrict__ Xb,
                                              const ushort_t* __restrict__ Wb,
                                              const float* __restrict__ bias,
                                              const float* __restrict__ bnA,
                                              const float* __restrict__ bnS,
                                              ushort_t* __restrict__ T,
                                              float* __restrict__ gsum,
                                              float* __restrict__ gsq,
                                              int Kt, int Nout) {
    __shared__ __align__(16) char smem[36864];
    ushort_t (*sA)[128 * 32] = (ushort_t(*)[128 * 32])(smem);            // 16 KB
    ushort_t (*sB)[128 * 32] = (ushort_t(*)[128 * 32])(smem + 16384);    // 16 KB
    ushort_t* cb = (ushort_t*)smem;                                      // bounce 34816 B
    float* redS = (float*)(smem + 34816);                                // 1 KB
    float* redQ = (float*)(smem + 35840);                                // 1 KB

    int tid = threadIdx.x;
    int l = tid & 63;
    int w = tid >> 6;
    int wr = w >> 1, wc = w & 1;
    int j0 = blockIdx.x * 128, o0 = blockIdx.y * 128;

    f32x4 acc[4][4] = {};
    int nt = Kt >> 5;

    // W staging (always direct-to-LDS, pre-swizzled source chunk)
    auto stageW = [&](int buf, int k0) {
#pragma unroll
        for (int e = 0; e < 2; ++e) {
            int i = e * 256 + tid;
            int row = i >> 2;
            int g = (i & 3) ^ ((row >> 1) & 3);
            const ushort_t* gb = Wb + (size_t)(o0 + row) * Kt + k0 + g * 8;
            __builtin_amdgcn_global_load_lds(
                (const __attribute__((address_space(1))) void*)gb,
                (__attribute__((address_space(3))) void*)&sB[buf][i * 8], 16, 0, 0);
        }
    };
    // X staging, FB=false: direct-to-LDS like W
    auto stageX = [&](int buf, int k0) {
#pragma unroll
        for (int e = 0; e < 2; ++e) {
            int i = e * 256 + tid;
            int row = i >> 2;
            int g = (i & 3) ^ ((row >> 1) & 3);
            const ushort_t* ga = Xb + (size_t)(j0 + row) * Kt + k0 + g * 8;
            __builtin_amdgcn_global_load_lds(
                (const __attribute__((address_space(1))) void*)ga,
                (__attribute__((address_space(3))) void*)&sA[buf][i * 8], 16, 0, 0);
        }
    };
    // X staging, FB=true: global->reg (linear chunk), BN+ReLU, ds_write to the
    // SAME swizzled slot layout the compute-side read expects.
    uint4 xv[2];
    float4 xa0[2], xa1[2], xs0[2], xs1[2];
    auto xload = [&](int k0) {
#pragma unroll
        for (int e = 0; e < 2; ++e) {
            int i = e * 256 + tid;
            int row = i >> 2, c = i & 3;
            xv[e] = *(const uint4*)(Xb + (size_t)(j0 + row) * Kt + k0 + c * 8);
            xa0[e] = *(const float4*)(bnA + k0 + c * 8);
            xa1[e] = *(const float4*)(bnA + k0 + c * 8 + 4);
            xs0[e] = *(const float4*)(bnS + k0 + c * 8);
            xs1[e] = *(const float4*)(bnS + k0 + c * 8 + 4);
        }
    };
    auto xstore = [&](int buf) {
#pragma unroll
        for (int e = 0; e < 2; ++e) {
            int i = e * 256 + tid;
            int row = i >> 2, c = i & 3;
            int slot = c ^ ((row >> 1) & 3);
            const ushort_t* pu = (const ushort_t*)&xv[e];
            ushort_t tmp[8];
            tmp[0] = f2bf(fmaxf(xa0[e].x * bf2f(pu[0]) + xs0[e].x, 0.f));
            tmp[1] = f2bf(fmaxf(xa0[e].y * bf2f(pu[1]) + xs0[e].y, 0.f));
            tmp[2] = f2bf(fmaxf(xa0[e].z * bf2f(pu[2]) + xs0[e].z, 0.f));
            tmp[3] = f2bf(fmaxf(xa0[e].w * bf2f(pu[3]) + xs0[e].w, 0.f));
            tmp[4] = f2bf(fmaxf(xa1[e].x * bf2f(pu[4]) + xs1[e].x, 0.f));
            tmp[5] = f2bf(fmaxf(xa1[e].y * bf2f(pu[5]) + xs1[e].y, 0.f));
            tmp[6] = f2bf(fmaxf(xa1[e].z * bf2f(pu[6]) + xs1[e].z, 0.f));
            tmp[7] = f2bf(fmaxf(xa1[e].w * bf2f(pu[7]) + xs1[e].w, 0.f));
            *(uint4*)&sA[buf][row * 32 + slot * 8] = *(const uint4*)tmp;
        }
    };

    // prologue
    stageW(0, 0);
    if (FB) { xload(0); xstore(0); }
    else    { stageX(0, 0); }
    __syncthreads();

    for (int t = 0; t < nt; ++t) {
        int cur = t & 1;
        if (t + 1 < nt) {
            stageW(cur ^ 1, (t + 1) << 5);
            if (FB) xload((t + 1) << 5);
            else    stageX(cur ^ 1, (t + 1) << 5);
        }

        bf16x8 av[4], bv[4];
#pragma unroll
        for (int mi = 0; mi < 4; ++mi) {
            int r = wr * 64 + mi * 16 + (l & 15);
            int sl = (l >> 4) ^ ((r >> 1) & 3);
            av[mi] = *(const bf16x8*)&sA[cur][r * 32 + sl * 8];
        }
#pragma unroll
        for (int ni = 0; ni < 4; ++ni) {
            int r = wc * 64 + ni * 16 + (l & 15);
            int sl = (l >> 4) ^ ((r >> 1) & 3);
            bv[ni] = *(const bf16x8*)&sB[cur][r * 32 + sl * 8];
        }
#pragma unroll
        for (int mi = 0; mi < 4; ++mi)
#pragma unroll
            for (int ni = 0; ni < 4; ++ni)
                acc[mi][ni] = __builtin_amdgcn_mfma_f32_16x16x32_bf16(av[mi], bv[ni],
                                                                      acc[mi][ni], 0, 0, 0);
        if (FB && t + 1 < nt) xstore(cur ^ 1);   // after MFMA: load latency hidden
        __syncthreads();
    }

    // ---- epilogue: stats from regs + bounce acc -> LDS -> coalesced stores
    float csum[4], csq[4];
#pragma unroll
    for (int ni = 0; ni < 4; ++ni) { csum[ni] = 0.f; csq[ni] = 0.f; }

#pragma unroll
    for (int ni = 0; ni < 4; ++ni) {
        int oc = wc * 64 + ni * 16 + (l & 15);
        float bi = bias[o0 + oc];
#pragma unroll
        for (int mi = 0; mi < 4; ++mi) {
            int jr = wr * 64 + mi * 16 + (l >> 4) * 4;
#pragma unroll
            for (int r = 0; r < 4; ++r) {
                float v = acc[mi][ni][r] + bi;
                csum[ni] += v;
                csq[ni] += v * v;
                cb[(jr + r) * 136 + oc] = f2bf(v);
            }
        }
    }

#pragma unroll
    for (int ni = 0; ni < 4; ++ni) {
        float s = csum[ni], q = csq[ni];
        s += __shfl_xor(s, 16); s += __shfl_xor(s, 32);
        q += __shfl_xor(q, 16); q += __shfl_xor(q, 32);
        if ((l & 48) == 0) {
            int oc = wc * 64 + ni * 16 + (l & 15);
            redS[oc * 2 + wr] = s;
            redQ[oc * 2 + wr] = q;
        }
    }
    __syncthreads();

    if (tid < 128) {
        atomicAdd(&gsum[o0 + tid], redS[tid * 2] + redS[tid * 2 + 1]);
        atomicAdd(&gsq[o0 + tid], redQ[tid * 2] + redQ[tid * 2 + 1]);
    }
#pragma unroll
    for (int p = 0; p < 8; ++p) {
        int idx = p * 256 + tid;
        int jr = idx >> 4, oc8 = (idx & 15) * 8;
        uint4 v = *(const uint4*)&cb[jr * 136 + oc8];
        *(uint4*)&T[(size_t)(j0 + jr) * Nout + o0 + oc8] = v;
    }
}

// ---------------------------------------------------------------------------
__global__ void k_affine(const float* __restrict__ gsum, const float* __restrict__ gsq,
                         const float* __restrict__ g, const float* __restrict__ be,
                         float* __restrict__ A, float* __restrict__ S, int C) {
    int o = blockIdx.x * 256 + threadIdx.x;
    if (o >= C) return;
    float mean = gsum[o] / (float)J_;
    float var = gsq[o] / (float)J_ - mean * mean;
    float a = g[o] * rsqrtf(var + BN_EPS);
    A[o] = a;
    S[o] = be[o] - a * mean;
}

// ---------------------------------------------------------------------------
// T2 [J][256] bf16 + BN affine + ReLU -> out [B][256][N] fp32 (transpose)
__global__ __launch_bounds__(256) void k_final(const ushort_t* __restrict__ T2,
                                               const float* __restrict__ A,
                                               const float* __restrict__ S,
                                               float* __restrict__ out) {
    __shared__ float tile[64][65];
    int tid = threadIdx.x;
    int jb = blockIdx.z * N_ + blockIdx.x * 64;
    int o0 = blockIdx.y * 64;

    int r = tid >> 2, cq = (tid & 3) * 16;
    uint4 v = *(const uint4*)&T2[(size_t)(jb + r) * 256 + o0 + cq];
    ushort_t* pu = (ushort_t*)&v;
#pragma unroll
    for (int i = 0; i < 8; i++) {
        int o = o0 + cq + i;
        tile[r][cq + i] = fmaxf(A[o] * bf2f(pu[i]) + S[o], 0.f);
    }
    uint4 v2 = *(const uint4*)&T2[(size_t)(jb + r) * 256 + o0 + cq + 8];
    pu = (ushort_t*)&v2;
#pragma unroll
    for (int i = 0; i < 8; i++) {
        int o = o0 + cq + 8 + i;
        tile[r][cq + 8 + i] = fmaxf(A[o] * bf2f(pu[i]) + S[o], 0.f);
    }
    __syncthreads();

    int ro = tid >> 2, jq = (tid & 3) * 16;
    float* orow = out + ((size_t)blockIdx.z * 256 + o0 + ro) * N_ + blockIdx.x * 64 + jq;
#pragma unroll
    for (int h = 0; h < 4; h++) {
        float4 ov = {tile[jq + h * 4 + 0][ro], tile[jq + h * 4 + 1][ro],
                     tile[jq + h * 4 + 2][ro], tile[jq + h * 4 + 3][ro]};
        *(float4*)(orow + h * 4) = ov;
    }
}

// ---------------------------------------------------------------------------
extern "C" void kernel_launch(void* const* d_in, const int* in_sizes, int n_in,
                              void* d_out, int out_size, void* d_ws, size_t ws_size,
                              hipStream_t stream) {
    (void)in_sizes; (void)n_in; (void)out_size; (void)ws_size;
    const float* xyz1    = (const float*)d_in[0];
    const float* xyz2    = (const float*)d_in[1];
    const float* points1 = (const float*)d_in[2];
    const float* points2 = (const float*)d_in[3];
    const float* feature = (const float*)d_in[4];
    const float* W0 = (const float*)d_in[5];
    const float* b0 = (const float*)d_in[6];
    const float* g0 = (const float*)d_in[7];
    const float* be0 = (const float*)d_in[8];
    const float* W1 = (const float*)d_in[9];
    const float* b1 = (const float*)d_in[10];
    const float* g1 = (const float*)d_in[11];
    const float* be1 = (const float*)d_in[12];
    const float* W2 = (const float*)d_in[13];
    const float* b2 = (const float*)d_in[14];
    const float* g2 = (const float*)d_in[15];
    const float* be2 = (const float*)d_in[16];

    char* ws = (char*)d_ws;
    size_t off = 0;
    auto carve = [&](size_t bytes) { char* p = ws + off; off += (bytes + 255) & ~(size_t)255; return p; };

    ushort_t* XT  = (ushort_t*)carve((size_t)J_ * KP0 * 2);
    ushort_t* T0  = (ushort_t*)carve((size_t)J_ * 512 * 2);
    ushort_t* T1  = (ushort_t*)carve((size_t)J_ * 512 * 2);
    ushort_t* T2  = (ushort_t*)carve((size_t)J_ * 256 * 2);
    float*    p2t = (float*)carve((size_t)B_ * S_ * D2_ * 4);
    float*    nnp = (float*)carve((size_t)J_ * 64 * 4);
    ushort_t* Wb0 = (ushort_t*)carve((size_t)512 * KP0 * 2);
    ushort_t* Wb1 = (ushort_t*)carve((size_t)512 * K12 * 2);
    ushort_t* Wb2 = (ushort_t*)carve((size_t)256 * K12 * 2);
    float*    st  = (float*)carve(2560 * 4);
    float*    af  = (float*)carve(2560 * 4);
    float *gs0 = st, *gq0 = st + 512, *gs1 = st + 1024, *gq1 = st + 1536, *gs2 = st + 2048, *gq2 = st + 2304;
    float *A0 = af, *S0 = af + 512, *A1 = af + 1024, *S1 = af + 1536, *A2 = af + 2048, *S2 = af + 2304;

    k_zero<<<dim3(10), 256, 0, stream>>>(st, 2560);
    k_prep_w<<<dim3((512 * KP0 + 255) / 256), 256, 0, stream>>>(W0, Wb0, 512, CIN_, KP0);
    k_prep_w<<<dim3((512 * K12 + 255) / 256), 256, 0, stream>>>(W1, Wb1, 512, 512, K12);
    k_prep_w<<<dim3((512 * 256 + 255) / 256), 256, 0, stream>>>(W2, Wb2, 256, 512, K12);
    k_transpose_p2<<<dim3(S_ / 32, D2_ / 32, B_), dim3(32, 8), 0, stream>>>(points2, p2t);
    k_p1t<<<dim3(N_ / 32, B_), 256, 0, stream>>>(points1, XT);
    k_scan<<<dim3(J_ / 512, 8), 512, 0, stream>>>(xyz1, xyz2, feature, nnp);
    k_nn2<<<dim3(N_ / 4, B_), 256, 0, stream>>>(feature, p2t, nnp, XT);

    k_gemm<false><<<dim3(J_ / 128, 4), 256, 0, stream>>>(XT, Wb0, b0, nullptr, nullptr, T0, gs0, gq0, KP0, 512);
    k_affine<<<dim3(2), 256, 0, stream>>>(gs0, gq0, g0, be0, A0, S0, 512);

    k_gemm<true><<<dim3(J_ / 128, 4), 256, 0, stream>>>(T0, Wb1, b1, A0, S0, T1, gs1, gq1, K12, 512);
    k_affine<<<dim3(2), 256, 0, stream>>>(gs1, gq1, g1, be1, A1, S1, 512);

    k_gemm<true><<<dim3(J_ / 128, 2), 256, 0, stream>>>(T1, Wb2, b2, A1, S1, T2, gs2, gq2, K12, 256);
    k_affine<<<dim3(1), 256, 0, stream>>>(gs2, gq2, g2, be2, A2, S2, 256);

    k_final<<<dim3(N_ / 64, 4, B_), 256, 0, stream>>>(T2, A2, S2, (float*)d_out);
}

// Round 8
// 217.830 us; speedup vs baseline: 3.2665x; 1.0083x over previous
//
#include <hip/hip_runtime.h>

#define B_   8
#define N_   4096
#define S_   1024
#define M_   2048
#define D1_  128
#define D2_  256
#define CIN_ 388
#define KP0  416          // K of layer0, padded to 13*32
#define K12  512          // K of layers 1,2
#define J_   (B_ * N_)    // 32768
#define SS   (S_ / 8)     // 128 candidates per eighth
#define MM   (M_ / 8)     // 256 keypoints per eighth
#define BN_EPS 1e-5f

typedef __bf16 bf16x8 __attribute__((ext_vector_type(8)));
typedef float  f32x4  __attribute__((ext_vector_type(4)));
typedef unsigned short ushort_t;

__device__ __forceinline__ float mulrn(float a, float b) { return __fmul_rn(a, b); }
__device__ __forceinline__ float addrn(float a, float b) { return __fadd_rn(a, b); }
__device__ __forceinline__ float subrn(float a, float b) { return __fsub_rn(a, b); }
__device__ __forceinline__ float norm3(float x, float y, float z) {
    return addrn(addrn(mulrn(x, x), mulrn(y, y)), mulrn(z, z));
}
__device__ __forceinline__ ushort_t f2bf(float f) {  // RNE
    unsigned int u = __float_as_uint(f);
    return (ushort_t)((u + 0x7FFFu + ((u >> 16) & 1u)) >> 16);
}
__device__ __forceinline__ float bf2f(ushort_t u) {
    return __uint_as_float(((unsigned int)u) << 16);
}
// lexicographic (d, idx) compare — reproduces stable top-k tie-breaking
__device__ __forceinline__ bool plt(float da, int ia, float db, int ib) {
    return (da < db) || (da == db && ia < ib);
}

// ---------------------------------------------------------------------------
// points2 [B][D2][S] -> p2t [B][S][D2]  (fp32, feeds exact interp math)
__global__ __launch_bounds__(256) void k_transpose_p2(const float* __restrict__ p2,
                                                      float* __restrict__ p2t) {
    __shared__ float tile[32][33];
    int b = blockIdx.z;
    int s0 = blockIdx.x * 32, c0 = blockIdx.y * 32;
    int tx = threadIdx.x, ty = threadIdx.y;  // 32 x 8
#pragma unroll
    for (int i = 0; i < 4; i++)
        tile[ty + i * 8][tx] = p2[(size_t)b * D2_ * S_ + (size_t)(c0 + ty + i * 8) * S_ + s0 + tx];
    __syncthreads();
#pragma unroll
    for (int i = 0; i < 4; i++)
        p2t[(size_t)b * S_ * D2_ + (size_t)(s0 + ty + i * 8) * D2_ + c0 + tx] = tile[tx][ty + i * 8];
}

// ---------------------------------------------------------------------------
// W [O][C] fp32 -> Wb [O][Kp] bf16, zero-padded cols (already k-contiguous)
__global__ __launch_bounds__(256) void k_prep_w(const float* __restrict__ W,
                                                ushort_t* __restrict__ Wb, int O, int C, int Kp) {
    int i = blockIdx.x * 256 + threadIdx.x;
    if (i >= O * Kp) return;
    int o = i / Kp, k = i - o * Kp;
    Wb[i] = (k < C) ? f2bf(W[(size_t)o * C + k]) : (ushort_t)0;
}

// ---------------------------------------------------------------------------
__global__ void k_zero(float* p, int n) {
    int i = blockIdx.x * 256 + threadIdx.x;
    if (i < n) p[i] = 0.f;
}

// ---------------------------------------------------------------------------
// points1 [B][D1][N] fp32 -> XT[j][0:128] bf16 (LDS tile transpose)
__global__ __launch_bounds__(256) void k_p1t(const float* __restrict__ p1,
                                             ushort_t* __restrict__ XT) {
    __shared__ ushort_t tile[32][132];
    int b = blockIdx.y;
    int n0 = blockIdx.x * 32;
    int t = threadIdx.x;

    {
        int nl = t & 31, cq = t >> 5;
#pragma unroll
        for (int k = 0; k < 16; k++) {
            int c = cq * 16 + k;
            tile[nl][c] = f2bf(p1[(size_t)b * D1_ * N_ + (size_t)c * N_ + n0 + nl]);
        }
    }
    __syncthreads();
    {
        int nl = t >> 3, sub = t & 7;
        size_t j = (size_t)b * N_ + n0 + nl;
#pragma unroll
        for (int k = 0; k < 4; k++) {
            int chunk = k * 8 + sub;
            *(uint2*)&XT[j * KP0 + chunk * 4] = *(const uint2*)&tile[nl][chunk * 4];
        }
    }
}

// ---------------------------------------------------------------------------
// Scan phase: one THREAD per query, one candidate-EIGHTH per block.
__global__ __launch_bounds__(512) void k_scan(const float* __restrict__ xyz1,
                                              const float* __restrict__ xyz2,
                                              const float* __restrict__ feature,
                                              float* __restrict__ outp) {
    __shared__ float4 sL[SS];
    __shared__ float4 fL[MM];
    int tid = threadIdx.x;
    int e = blockIdx.y;
    int j = blockIdx.x * 512 + tid;
    int b = blockIdx.x >> 3;           // 8 blocks.x per batch (4096/512)
    int n = j & (N_ - 1);

    for (int i = tid; i < SS + MM; i += 512) {
        if (i < SS) {
            int s = e * SS + i;
            float x = xyz2[(size_t)b * 3 * S_ + s];
            float y = xyz2[(size_t)b * 3 * S_ + S_ + s];
            float z = xyz2[(size_t)b * 3 * S_ + 2 * S_ + s];
            sL[i] = make_float4(x, y, z, norm3(x, y, z));
        } else {
            int m = e * MM + (i - SS);
            float4 f = *(const float4*)(feature + (size_t)b * M_ * 4 + (size_t)m * 4);
            fL[i - SS] = make_float4(f.y, f.z, f.w, norm3(f.y, f.z, f.w));
        }
    }
    __syncthreads();

    float qx = xyz1[(size_t)b * 3 * N_ + n];
    float qy = xyz1[(size_t)b * 3 * N_ + N_ + n];
    float qz = xyz1[(size_t)b * 3 * N_ + 2 * N_ + n];
    float qn = norm3(qx, qy, qz);

    float d0 = 1e30f, d1 = 1e30f, d2 = 1e30f;
    int i0 = 0, i1 = 0, i2 = 0;
#pragma unroll 4
    for (int i = 0; i < SS; i++) {
        float4 c = sL[i];
        float dot = addrn(addrn(mulrn(qx, c.x), mulrn(qy, c.y)), mulrn(qz, c.z));
        float d = subrn(addrn(qn, c.w), mulrn(2.0f, dot));
        int s = e * SS + i;
        bool l0 = d < d0, l1 = d < d1, l2 = d < d2;
        d2 = l1 ? d1 : (l2 ? d : d2);  i2 = l1 ? i1 : (l2 ? s : i2);
        d1 = l0 ? d0 : (l1 ? d : d1);  i1 = l0 ? i0 : (l1 ? s : i1);
        d0 = l0 ? d  : d0;             i0 = l0 ? s  : i0;
    }

    float dm = 1e30f; int im = 0;
#pragma unroll 4
    for (int i = 0; i < MM; i++) {
        float4 c = fL[i];
        float dot = addrn(addrn(mulrn(qx, c.x), mulrn(qy, c.y)), mulrn(qz, c.z));
        float d = subrn(addrn(qn, c.w), mulrn(2.0f, dot));
        if (d < dm) { dm = d; im = e * MM + i; }
    }

    float* o = outp + ((size_t)j * 8 + e) * 8;
    float4 v0 = {d0, d1, d2, dm};
    float4 v1 = {__int_as_float(i0), __int_as_float(i1), __int_as_float(i2), __int_as_float(im)};
    *(float4*)o = v0;
    *(float4*)(o + 4) = v1;
}

// ---------------------------------------------------------------------------
// Merge + assembly: one WAVE per query; 3-step lexicographic butterfly merge.
__global__ __launch_bounds__(256) void k_nn2(const float* __restrict__ feature,
                                             const float* __restrict__ p2t,
                                             const float* __restrict__ outp,
                                             ushort_t* __restrict__ XT) {
    int bq = blockIdx.y;
    int wid = threadIdx.x >> 6;
    int l = threadIdx.x & 63;
    int n = blockIdx.x * 4 + wid;
    size_t j = (size_t)bq * N_ + n;
    const float* fb = feature + (size_t)bq * M_ * 4;

    float d0 = 1e30f, d1 = 1e30f, d2 = 1e30f, dm = 1e30f;
    int i0 = 0, i1 = 0, i2 = 0, im = 0;
    if (l < 8) {
        const float* o = outp + (j * 8 + l) * 8;
        float4 a = *(const float4*)o;
        float4 bi = *(const float4*)(o + 4);
        d0 = a.x; d1 = a.y; d2 = a.z; dm = a.w;
        i0 = __float_as_int(bi.x); i1 = __float_as_int(bi.y);
        i2 = __float_as_int(bi.z); im = __float_as_int(bi.w);
    }

#pragma unroll
    for (int off = 1; off < 8; off <<= 1) {
        float e0 = __shfl_xor(d0, off), e1 = __shfl_xor(d1, off), e2 = __shfl_xor(d2, off);
        int   f0 = __shfl_xor(i0, off), f1 = __shfl_xor(i1, off), f2 = __shfl_xor(i2, off);
        bool c0 = plt(e0, f0, d0, i0);
        float m0d = c0 ? e0 : d0; int m0i = c0 ? f0 : i0;
        float x0d = c0 ? d0 : e0; int x0i = c0 ? i0 : f0;
        bool c1 = plt(e1, f1, d1, i1);
        float n1d = c1 ? e1 : d1; int n1i = c1 ? f1 : i1;
        float z1d = c1 ? d1 : e1; int z1i = c1 ? i1 : f1;
        bool c2 = plt(e2, f2, d2, i2);
        float w2d = c2 ? e2 : d2; int w2i = c2 ? f2 : i2;
        bool c3 = plt(n1d, n1i, x0d, x0i);
        float r1d = c3 ? n1d : x0d; int r1i = c3 ? n1i : x0i;
        float t2d = c3 ? x0d : n1d; int t2i = c3 ? x0i : n1i;
        bool c4 = plt(t2d, t2i, z1d, z1i);
        float u2d = c4 ? t2d : z1d; int u2i = c4 ? t2i : z1i;
        bool c5 = plt(w2d, w2i, u2d, u2i);
        float r2d = c5 ? w2d : u2d; int r2i = c5 ? w2i : u2i;
        d0 = m0d; i0 = m0i; d1 = r1d; i1 = r1i; d2 = r2d; i2 = r2i;

        float ed = __shfl_xor(dm, off); int ei = __shfl_xor(im, off);
        if (plt(ed, ei, dm, im)) { dm = ed; im = ei; }
    }

    d0 = __shfl(d0, 0); d1 = __shfl(d1, 0); d2 = __shfl(d2, 0);
    i0 = __shfl(i0, 0); i1 = __shfl(i1, 0); i2 = __shfl(i2, 0);
    im = __shfl(im, 0);

    float w0 = 1.0f / addrn(d0, 1e-8f);
    float w1 = 1.0f / addrn(d1, 1e-8f);
    float w2 = 1.0f / addrn(d2, 1e-8f);
    float wsum = addrn(addrn(w0, w1), w2);
    w0 = w0 / wsum; w1 = w1 / wsum; w2 = w2 / wsum;

    ushort_t* xr = XT + j * KP0;
    const float* r0 = p2t + (size_t)bq * S_ * D2_ + (size_t)i0 * D2_;
    const float* r1 = p2t + (size_t)bq * S_ * D2_ + (size_t)i1 * D2_;
    const float* r2 = p2t + (size_t)bq * S_ * D2_ + (size_t)i2 * D2_;
    {
        int c = l * 4;
        float4 a = *(const float4*)(r0 + c);
        float4 bb = *(const float4*)(r1 + c);
        float4 cc = *(const float4*)(r2 + c);
        ushort_t tmp[4];
        tmp[0] = f2bf(addrn(addrn(mulrn(a.x, w0), mulrn(bb.x, w1)), mulrn(cc.x, w2)));
        tmp[1] = f2bf(addrn(addrn(mulrn(a.y, w0), mulrn(bb.y, w1)), mulrn(cc.y, w2)));
        tmp[2] = f2bf(addrn(addrn(mulrn(a.z, w0), mulrn(bb.z, w1)), mulrn(cc.z, w2)));
        tmp[3] = f2bf(addrn(addrn(mulrn(a.w, w0), mulrn(bb.w, w1)), mulrn(cc.w, w2)));
        *(uint2*)&xr[D1_ + c] = *(uint2*)tmp;
    }
    if (l < 8) {
        uint2 v = {0u, 0u};
        if (l == 0) {
            float4 nf = *(const float4*)(fb + (size_t)im * 4);
            ushort_t tmp[4] = {f2bf(nf.x), f2bf(nf.y), f2bf(nf.z), f2bf(nf.w)};
            v = *(uint2*)tmp;
        }
        *(uint2*)&xr[384 + l * 4] = v;
    }
}

// ---------------------------------------------------------------------------
// bf16 MFMA GEMM: T[j][o] = X[j][:]·W[o][:] + bias[o], fused BN-stat atomics.
// Triple-buffered LDS, prefetch distance 2, counted s_waitcnt vmcnt(4) + raw
// s_barrier (never drain to 0 in steady state). Coalesced C-write via LDS
// bounce tile [128][136].
__global__ __launch_bounds__(256) void k_gemm(const ushort_t* __restrict__ Xb,
                                              const ushort_t* __restrict__ Wb,
                                              const float* __restrict__ bias,
                                              ushort_t* __restrict__ T,
                                              float* __restrict__ gsum,
                                              float* __restrict__ gsq,
                                              int Kt, int Nout) {
    // 3 buffers x 16 KB (sA 8KB | sB 8KB) = 49152 B; stats 2 KB after.
    __shared__ __align__(16) char smem[51200];
    ushort_t* cb = (ushort_t*)smem;                    // bounce: 34816 B (aliases bufs)
    float* redS = (float*)(smem + 49152);              // 1 KB
    float* redQ = (float*)(smem + 50176);              // 1 KB

    int tid = threadIdx.x;
    int l = tid & 63;
    int w = tid >> 6;
    int wr = w >> 1, wc = w & 1;
    int j0 = blockIdx.x * 128, o0 = blockIdx.y * 128;

    f32x4 acc[4][4] = {};
    int nt = Kt >> 5;

    auto stage = [&](int buf, int kt) {
        int k0 = kt << 5;
        ushort_t* base = (ushort_t*)(smem + buf * 16384);
#pragma unroll
        for (int e = 0; e < 2; ++e) {
            int i = e * 256 + tid;
            int row = i >> 2;
            int g = (i & 3) ^ ((row >> 1) & 3);   // pre-swizzled source chunk
            const ushort_t* ga = Xb + (size_t)(j0 + row) * Kt + k0 + g * 8;
            __builtin_amdgcn_global_load_lds(
                (const __attribute__((address_space(1))) void*)ga,
                (__attribute__((address_space(3))) void*)&base[i * 8], 16, 0, 0);
            const ushort_t* gb = Wb + (size_t)(o0 + row) * Kt + k0 + g * 8;
            __builtin_amdgcn_global_load_lds(
                (const __attribute__((address_space(1))) void*)gb,
                (__attribute__((address_space(3))) void*)&base[4096 + i * 8], 16, 0, 0);
        }
    };

    // prologue: 2 tiles in flight, wait only the first (vmcnt(4))
    stage(0, 0);
    stage(1, 1);
    asm volatile("s_waitcnt vmcnt(4)" ::: "memory");
    __builtin_amdgcn_s_barrier();

    for (int t = 0; t < nt; ++t) {
        if (t + 2 < nt) stage((t + 2) % 3, t + 2);

        ushort_t* base = (ushort_t*)(smem + (t % 3) * 16384);
        bf16x8 av[4], bv[4];
#pragma unroll
        for (int mi = 0; mi < 4; ++mi) {
            int r = wr * 64 + mi * 16 + (l & 15);
            int sl = (l >> 4) ^ ((r >> 1) & 3);
            av[mi] = *(const bf16x8*)&base[r * 32 + sl * 8];
        }
#pragma unroll
        for (int ni = 0; ni < 4; ++ni) {
            int r = wc * 64 + ni * 16 + (l & 15);
            int sl = (l >> 4) ^ ((r >> 1) & 3);
            bv[ni] = *(const bf16x8*)&base[4096 + r * 32 + sl * 8];
        }
#pragma unroll
        for (int mi = 0; mi < 4; ++mi)
#pragma unroll
            for (int ni = 0; ni < 4; ++ni)
                acc[mi][ni] = __builtin_amdgcn_mfma_f32_16x16x32_bf16(av[mi], bv[ni],
                                                                      acc[mi][ni], 0, 0, 0);
        // end-of-iter: need stage(t+1) complete; stage(t+2)'s 4 loads may fly.
        if (t + 2 < nt)      asm volatile("s_waitcnt vmcnt(4)" ::: "memory");
        else if (t + 1 < nt) asm volatile("s_waitcnt vmcnt(0)" ::: "memory");
        __builtin_amdgcn_s_barrier();
    }

    // ---- epilogue: stats from regs + bounce acc -> LDS -> coalesced stores
    float csum[4], csq[4];
#pragma unroll
    for (int ni = 0; ni < 4; ++ni) { csum[ni] = 0.f; csq[ni] = 0.f; }

#pragma unroll
    for (int ni = 0; ni < 4; ++ni) {
        int oc = wc * 64 + ni * 16 + (l & 15);
        float bi = bias[o0 + oc];
#pragma unroll
        for (int mi = 0; mi < 4; ++mi) {
            int jr = wr * 64 + mi * 16 + (l >> 4) * 4;
#pragma unroll
            for (int r = 0; r < 4; ++r) {
                float v = acc[mi][ni][r] + bi;
                csum[ni] += v;
                csq[ni] += v * v;
                cb[(jr + r) * 136 + oc] = f2bf(v);
            }
        }
    }

#pragma unroll
    for (int ni = 0; ni < 4; ++ni) {
        float s = csum[ni], q = csq[ni];
        s += __shfl_xor(s, 16); s += __shfl_xor(s, 32);
        q += __shfl_xor(q, 16); q += __shfl_xor(q, 32);
        if ((l & 48) == 0) {
            int oc = wc * 64 + ni * 16 + (l & 15);
            redS[oc * 2 + wr] = s;
            redQ[oc * 2 + wr] = q;
        }
    }
    __syncthreads();

    if (tid < 128) {
        atomicAdd(&gsum[o0 + tid], redS[tid * 2] + redS[tid * 2 + 1]);
        atomicAdd(&gsq[o0 + tid], redQ[tid * 2] + redQ[tid * 2 + 1]);
    }
#pragma unroll
    for (int p = 0; p < 8; ++p) {
        int idx = p * 256 + tid;
        int jr = idx >> 4, oc8 = (idx & 15) * 8;
        uint4 v = *(const uint4*)&cb[jr * 136 + oc8];
        *(uint4*)&T[(size_t)(j0 + jr) * Nout + o0 + oc8] = v;
    }
}

// ---------------------------------------------------------------------------
__global__ void k_affine(const float* __restrict__ gsum, const float* __restrict__ gsq,
                         const float* __restrict__ g, const float* __restrict__ be,
                         float* __restrict__ A, float* __restrict__ S, int C) {
    int o = blockIdx.x * 256 + threadIdx.x;
    if (o >= C) return;
    float mean = gsum[o] / (float)J_;
    float var = gsq[o] / (float)J_ - mean * mean;
    float a = g[o] * rsqrtf(var + BN_EPS);
    A[o] = a;
    S[o] = be[o] - a * mean;
}

// ---------------------------------------------------------------------------
// In-place BN+ReLU on T [J][512] bf16 (channel = col = idx & 511)
__global__ __launch_bounds__(256) void k_norm(ushort_t* __restrict__ T,
                                              const float* __restrict__ A,
                                              const float* __restrict__ S) {
    size_t idx = ((size_t)blockIdx.x * 256 + threadIdx.x) * 8;
    int o = (int)(idx & 511);
    uint4 v = *(uint4*)&T[idx];
    ushort_t* pu = (ushort_t*)&v;
#pragma unroll
    for (int i = 0; i < 8; i++) {
        float f = bf2f(pu[i]);
        f = fmaxf(A[o + i] * f + S[o + i], 0.f);
        pu[i] = f2bf(f);
    }
    *(uint4*)&T[idx] = v;
}

// ---------------------------------------------------------------------------
// T2 [J][256] bf16 + BN affine + ReLU -> out [B][256][N] fp32 (transpose)
__global__ __launch_bounds__(256) void k_final(const ushort_t* __restrict__ T2,
                                               const float* __restrict__ A,
                                               const float* __restrict__ S,
                                               float* __restrict__ out) {
    __shared__ float tile[64][65];
    int tid = threadIdx.x;
    int jb = blockIdx.z * N_ + blockIdx.x * 64;
    int o0 = blockIdx.y * 64;

    int r = tid >> 2, cq = (tid & 3) * 16;
    uint4 v = *(const uint4*)&T2[(size_t)(jb + r) * 256 + o0 + cq];
    ushort_t* pu = (ushort_t*)&v;
#pragma unroll
    for (int i = 0; i < 8; i++) {
        int o = o0 + cq + i;
        tile[r][cq + i] = fmaxf(A[o] * bf2f(pu[i]) + S[o], 0.f);
    }
    uint4 v2 = *(const uint4*)&T2[(size_t)(jb + r) * 256 + o0 + cq + 8];
    pu = (ushort_t*)&v2;
#pragma unroll
    for (int i = 0; i < 8; i++) {
        int o = o0 + cq + 8 + i;
        tile[r][cq + 8 + i] = fmaxf(A[o] * bf2f(pu[i]) + S[o], 0.f);
    }
    __syncthreads();

    int ro = tid >> 2, jq = (tid & 3) * 16;
    float* orow = out + ((size_t)blockIdx.z * 256 + o0 + ro) * N_ + blockIdx.x * 64 + jq;
#pragma unroll
    for (int h = 0; h < 4; h++) {
        float4 ov = {tile[jq + h * 4 + 0][ro], tile[jq + h * 4 + 1][ro],
                     tile[jq + h * 4 + 2][ro], tile[jq + h * 4 + 3][ro]};
        *(float4*)(orow + h * 4) = ov;
    }
}

// ---------------------------------------------------------------------------
extern "C" void kernel_launch(void* const* d_in, const int* in_sizes, int n_in,
                              void* d_out, int out_size, void* d_ws, size_t ws_size,
                              hipStream_t stream) {
    (void)in_sizes; (void)n_in; (void)out_size; (void)ws_size;
    const float* xyz1    = (const float*)d_in[0];
    const float* xyz2    = (const float*)d_in[1];
    const float* points1 = (const float*)d_in[2];
    const float* points2 = (const float*)d_in[3];
    const float* feature = (const float*)d_in[4];
    const float* W0 = (const float*)d_in[5];
    const float* b0 = (const float*)d_in[6];
    const float* g0 = (const float*)d_in[7];
    const float* be0 = (const float*)d_in[8];
    const float* W1 = (const float*)d_in[9];
    const float* b1 = (const float*)d_in[10];
    const float* g1 = (const float*)d_in[11];
    const float* be1 = (const float*)d_in[12];
    const float* W2 = (const float*)d_in[13];
    const float* b2 = (const float*)d_in[14];
    const float* g2 = (const float*)d_in[15];
    const float* be2 = (const float*)d_in[16];

    char* ws = (char*)d_ws;
    size_t off = 0;
    auto carve = [&](size_t bytes) { char* p = ws + off; off += (bytes + 255) & ~(size_t)255; return p; };

    ushort_t* XT  = (ushort_t*)carve((size_t)J_ * KP0 * 2);
    ushort_t* T0  = (ushort_t*)carve((size_t)J_ * 512 * 2);
    ushort_t* T1  = (ushort_t*)carve((size_t)J_ * 512 * 2);
    ushort_t* T2  = (ushort_t*)carve((size_t)J_ * 256 * 2);
    float*    p2t = (float*)carve((size_t)B_ * S_ * D2_ * 4);
    float*    nnp = (float*)carve((size_t)J_ * 64 * 4);
    ushort_t* Wb0 = (ushort_t*)carve((size_t)512 * KP0 * 2);
    ushort_t* Wb1 = (ushort_t*)carve((size_t)512 * K12 * 2);
    ushort_t* Wb2 = (ushort_t*)carve((size_t)256 * K12 * 2);
    float*    st  = (float*)carve(2560 * 4);
    float*    af  = (float*)carve(2560 * 4);
    float *gs0 = st, *gq0 = st + 512, *gs1 = st + 1024, *gq1 = st + 1536, *gs2 = st + 2048, *gq2 = st + 2304;
    float *A0 = af, *S0 = af + 512, *A1 = af + 1024, *S1 = af + 1536, *A2 = af + 2048, *S2 = af + 2304;

    k_zero<<<dim3(10), 256, 0, stream>>>(st, 2560);
    k_prep_w<<<dim3((512 * KP0 + 255) / 256), 256, 0, stream>>>(W0, Wb0, 512, CIN_, KP0);
    k_prep_w<<<dim3((512 * K12 + 255) / 256), 256, 0, stream>>>(W1, Wb1, 512, 512, K12);
    k_prep_w<<<dim3((512 * 256 + 255) / 256), 256, 0, stream>>>(W2, Wb2, 256, 512, K12);
    k_transpose_p2<<<dim3(S_ / 32, D2_ / 32, B_), dim3(32, 8), 0, stream>>>(points2, p2t);
    k_p1t<<<dim3(N_ / 32, B_), 256, 0, stream>>>(points1, XT);
    k_scan<<<dim3(J_ / 512, 8), 512, 0, stream>>>(xyz1, xyz2, feature, nnp);
    k_nn2<<<dim3(N_ / 4, B_), 256, 0, stream>>>(feature, p2t, nnp, XT);

    k_gemm<<<dim3(J_ / 128, 4), 256, 0, stream>>>(XT, Wb0, b0, T0, gs0, gq0, KP0, 512);
    k_affine<<<dim3(2), 256, 0, stream>>>(gs0, gq0, g0, be0, A0, S0, 512);
    k_norm<<<dim3((int)((size_t)J_ * 512 / 8 / 256)), 256, 0, stream>>>(T0, A0, S0);

    k_gemm<<<dim3(J_ / 128, 4), 256, 0, stream>>>(T0, Wb1, b1, T1, gs1, gq1, K12, 512);
    k_affine<<<dim3(2), 256, 0, stream>>>(gs1, gq1, g1, be1, A1, S1, 512);
    k_norm<<<dim3((int)((size_t)J_ * 512 / 8 / 256)), 256, 0, stream>>>(T1, A1, S1);

    k_gemm<<<dim3(J_ / 128, 2), 256, 0, stream>>>(T1, Wb2, b2, T2, gs2, gq2, K12, 256);
    k_affine<<<dim3(1), 256, 0, stream>>>(gs2, gq2, g2, be2, A2, S2, 256);

    k_final<<<dim3(N_ / 64, 4, B_), 256, 0, stream>>>(T2, A2, S2, (float*)d_out);
}